// Round 14
// baseline (278.424 us; speedup 1.0000x reference)
//
#include <hip/hip_runtime.h>
#include <hip/hip_fp16.h>

#define NNODES   100000
#define NFEAT    16
#define NEDGES   3200000
#define EH       1600000     // edges per half
#define NB       250         // dst buckets
#define NODES_PB 400         // 250*400 = 100000
#define NCH      125         // chunks per half
#define CHK      12800       // 125*12800 = 1600000
#define CAP      7168        // per-bucket-half capacity (mean 6400, sigma~80 -> +9.6s)

// ---------- K1: per-chunk bucket histogram over one half ----------
__global__ __launch_bounds__(1024) void hist_chunk(
    const int* __restrict__ dst, int ebase, int* __restrict__ cnt /*[NCH][NB]*/)
{
    __shared__ int h[NB];
    int c = blockIdx.x;
    for (int i = threadIdx.x; i < NB; i += 1024) h[i] = 0;
    __syncthreads();
    int base = ebase + c * CHK;
    for (int i = threadIdx.x; i < CHK; i += 1024) {
        int d = dst[base + i];
        atomicAdd(&h[d / NODES_PB], 1);
    }
    __syncthreads();
    for (int i = threadIdx.x; i < NB; i += 1024) cnt[c * NB + i] = h[i];
}

// ---------- K2: per-bucket exclusive scan over chunks ----------
__global__ __launch_bounds__(256) void scan_chunks(
    int* __restrict__ cnt, int* __restrict__ tot)
{
    __shared__ int x[256];
    int b = blockIdx.x, t = threadIdx.x;
    int v = (t < NCH) ? cnt[t * NB + b] : 0;
    x[t] = v;
    __syncthreads();
    for (int off = 1; off < 256; off <<= 1) {
        int y = (t >= off) ? x[t - off] : 0;
        __syncthreads();
        x[t] += y;
        __syncthreads();
    }
    if (t < NCH) cnt[t * NB + b] = x[t] - v;
    if (t == NCH - 1) tot[b] = x[t];
}

// ---------- K3: exclusive scan of bucket totals -> bb[NB+1] ----------
__global__ __launch_bounds__(256) void scan_tot(
    const int* __restrict__ tot, int* __restrict__ bb)
{
    __shared__ int x[256];
    int t = threadIdx.x;
    int v = (t < NB) ? tot[t] : 0;
    x[t] = v;
    __syncthreads();
    for (int off = 1; off < 256; off <<= 1) {
        int y = (t >= off) ? x[t - off] : 0;
        __syncthreads();
        x[t] += y;
        __syncthreads();
    }
    if (t < NB) bb[t] = x[t] - v;
    if (t == NB - 1) bb[NB] = x[t];
}

// ---------- K4: scatter edges of one half into bucket-major AoS slots ----------
// entry = 3 dwords: {src | dl<<17, half2(w0,w1), half2(w2,w3)}
__global__ __launch_bounds__(1024) void scatter_bins(
    const int*   __restrict__ src,
    const int*   __restrict__ dst,
    const float* __restrict__ wt,
    const float* __restrict__ lw,
    int ebase,
    const int*   __restrict__ cnt,
    const int*   __restrict__ bb,
    unsigned int* __restrict__ binsE)
{
    __shared__ int cur[NB];
    int c = blockIdx.x;
    for (int i = threadIdx.x; i < NB; i += 1024)
        cur[i] = bb[i] + cnt[c * NB + i];
    __syncthreads();
    int base = ebase + c * CHK;
    for (int i = threadIdx.x; i < CHK; i += 1024) {
        int e = base + i;
        int d = dst[e];
        int b  = d / NODES_PB;
        int dl = d - b * NODES_PB;
        float w = wt[e];
        __half2 w01 = __floats2half2_rn(w * lw[e],              w * lw[NEDGES + e]);
        __half2 w23 = __floats2half2_rn(w * lw[2 * NEDGES + e], w * lw[3 * NEDGES + e]);
        int slot = atomicAdd(&cur[b], 1);
        unsigned int* p = binsE + 3u * (unsigned int)slot;
        p[0] = (unsigned int)src[e] | ((unsigned int)dl << 17);
        p[1] = *(const unsigned int*)&w01;
        p[2] = *(const unsigned int*)&w23;
    }
}

// ---------- K5: per-bucket node sort, permutation in LDS, sequential flushes ----------
__global__ __launch_bounds__(512) void bucket_csr(
    const int*          __restrict__ bb,
    const unsigned int* __restrict__ binsE,
    unsigned int*       __restrict__ csrA,
    unsigned short*     __restrict__ w0,    // f16 bit patterns
    unsigned short*     __restrict__ w1,
    unsigned short*     __restrict__ w2,
    unsigned short*     __restrict__ w3,
    int*                __restrict__ offs)
{
    __shared__ unsigned int   regA[CAP];    // P1-P2b: sA ; P3-P4: {w0,w1} u16 planes
    __shared__ unsigned int   regC[CAP];    // P2-P2b: inv u16 ; P3-P4: {w2,w3} u16 planes
    __shared__ unsigned short pi[CAP];      // edge -> slot
    __shared__ int hist[NODES_PB];
    __shared__ int cur[NODES_PB];
    __shared__ int sc[512];                 // total ~75 KiB -> 2 blocks/CU
    int b  = blockIdx.x, t = threadIdx.x;
    int e0 = bb[b];
    int cnt = bb[b + 1] - e0;
    if (cnt > CAP) cnt = CAP;               // statistically impossible; guards corruption

    for (int i = t; i < NODES_PB; i += 512) hist[i] = 0;
    __syncthreads();
    // P1: stage word0 + node histogram
    for (int i = t; i < cnt; i += 512) {
        unsigned int a = binsE[3u * (unsigned int)(e0 + i)];
        regA[i] = a;
        atomicAdd(&hist[a >> 17], 1);
    }
    __syncthreads();
    // exclusive scan of 400 node counts
    int v = (t < NODES_PB) ? hist[t] : 0;
    sc[t] = v;
    __syncthreads();
    for (int off = 1; off < 512; off <<= 1) {
        int y = (t >= off) ? sc[t - off] : 0;
        __syncthreads();
        sc[t] += y;
        __syncthreads();
    }
    if (t < NODES_PB) {
        int excl = sc[t] - v;
        cur[t] = excl;
        offs[b * NODES_PB + t] = e0 + excl;
    }
    if (b == 0 && t == 0) offs[NNODES] = EH;
    __syncthreads();
    // P2: assign slots; build pi (edge->slot) and inv (slot->edge) in LDS
    unsigned short* inv = (unsigned short*)regC;
    for (int i = t; i < cnt; i += 512) {
        unsigned int a = regA[i];
        int slot = atomicAdd(&cur[a >> 17], 1);
        pi[i]  = (unsigned short)slot;
        inv[slot] = (unsigned short)i;
    }
    __syncthreads();
    // P2b: flush csrA SEQUENTIALLY (gather via inv)
    for (int s = t; s < cnt; s += 512) {
        csrA[e0 + s] = regA[inv[s]] & 0x1FFFFu;
    }
    __syncthreads();
    // P3: read weight words once; scatter f16 halves into LDS planes at pi[i]
    unsigned short* wA0 = (unsigned short*)regA;         // overwrites dead sA
    unsigned short* wA1 = wA0 + CAP;
    unsigned short* wC2 = (unsigned short*)regC;         // overwrites dead inv
    unsigned short* wC3 = wC2 + CAP;
    for (int i = t; i < cnt; i += 512) {
        unsigned int u01 = binsE[3u * (unsigned int)(e0 + i) + 1];
        unsigned int u23 = binsE[3u * (unsigned int)(e0 + i) + 2];
        int s = pi[i];
        wA0[s] = (unsigned short)(u01 & 0xFFFFu);
        wA1[s] = (unsigned short)(u01 >> 16);
        wC2[s] = (unsigned short)(u23 & 0xFFFFu);
        wC3[s] = (unsigned short)(u23 >> 16);
    }
    __syncthreads();
    // P4: flush all four planes SEQUENTIALLY
    for (int s = t; s < cnt; s += 512) {
        w0[e0 + s] = wA0[s];
        w1[e0 + s] = wA1[s];
        w2[e0 + s] = wC2[s];
        w3[e0 + s] = wC3[s];
    }
}

// ---------- K5b: convert h0 (f32) -> f16 table ----------
__global__ __launch_bounds__(256) void conv16(
    const float2* __restrict__ in, __half2* __restrict__ out, int n2)
{
    int i = blockIdx.x * 256 + threadIdx.x;
    if (i < n2) {
        float2 v = in[i];
        out[i] = __floats2half2_rn(v.x, v.y);
    }
}

// ---------- helpers ----------
__device__ __forceinline__ void edge8(
    const unsigned int* __restrict__ csrA, const unsigned short* __restrict__ wk,
    const __half2* __restrict__ h16, int j, int f2, float& ax, float& ay)
{
    unsigned int s = csrA[j];
    float w = __half2float(__ushort_as_half(wk[j]));
    float2 v = __half22float2(h16[s * 8 + f2]);
    ax = fmaf(w, v.x, ax);
    ay = fmaf(w, v.y, ay);
}

__device__ __forceinline__ void seg8(
    int j, int j1, const unsigned int* __restrict__ csrA,
    const unsigned short* __restrict__ wk, const __half2* __restrict__ h16,
    int f2, float& ax, float& ay)
{
    for (; j < j1; ++j) edge8(csrA, wk, h16, j, f2, ax, ay);
}

// ---------- K6: pull layer — 8 lanes/node, half2 gathers, 8 edges in flight ----------
template<bool SIG>
__global__ __launch_bounds__(256) void pull8(
    const int*            __restrict__ offs1,
    const int*            __restrict__ offs2,
    const unsigned int*   __restrict__ csrA1,
    const unsigned int*   __restrict__ csrA2,
    const unsigned short* __restrict__ wk1,
    const unsigned short* __restrict__ wk2,
    const __half2*        __restrict__ h16,   // [NNODES*8]
    const float2*         __restrict__ h0,    // [NNODES*8]
    void*                 __restrict__ hout)
{
    int t = blockIdx.x * 256 + threadIdx.x;
    int n = t >> 3;
    if (n >= NNODES) return;
    int f2 = t & 7;
    int j1 = offs1[n], e1 = offs1[n + 1];
    int j2 = offs2[n], e2 = offs2[n + 1];
    float ax1 = 0.f, ay1 = 0.f, ax2 = 0.f, ay2 = 0.f;

    // 8 edges in flight: 4 from each half
    while (j1 + 3 < e1 && j2 + 3 < e2) {
        unsigned int s0 = csrA1[j1],     s1 = csrA1[j1 + 1];
        unsigned int s2 = csrA1[j1 + 2], s3 = csrA1[j1 + 3];
        unsigned int s4 = csrA2[j2],     s5 = csrA2[j2 + 1];
        unsigned int s6 = csrA2[j2 + 2], s7 = csrA2[j2 + 3];
        float wa = __half2float(__ushort_as_half(wk1[j1]));
        float wb = __half2float(__ushort_as_half(wk1[j1 + 1]));
        float wc = __half2float(__ushort_as_half(wk1[j1 + 2]));
        float wd = __half2float(__ushort_as_half(wk1[j1 + 3]));
        float we = __half2float(__ushort_as_half(wk2[j2]));
        float wf = __half2float(__ushort_as_half(wk2[j2 + 1]));
        float wg = __half2float(__ushort_as_half(wk2[j2 + 2]));
        float wh = __half2float(__ushort_as_half(wk2[j2 + 3]));
        float2 v0 = __half22float2(h16[s0 * 8 + f2]);
        float2 v1 = __half22float2(h16[s1 * 8 + f2]);
        float2 v2 = __half22float2(h16[s2 * 8 + f2]);
        float2 v3 = __half22float2(h16[s3 * 8 + f2]);
        float2 v4 = __half22float2(h16[s4 * 8 + f2]);
        float2 v5 = __half22float2(h16[s5 * 8 + f2]);
        float2 v6 = __half22float2(h16[s6 * 8 + f2]);
        float2 v7 = __half22float2(h16[s7 * 8 + f2]);
        ax1 = fmaf(wa, v0.x, ax1); ay1 = fmaf(wa, v0.y, ay1);
        ax1 = fmaf(wb, v1.x, ax1); ay1 = fmaf(wb, v1.y, ay1);
        ax1 = fmaf(wc, v2.x, ax1); ay1 = fmaf(wc, v2.y, ay1);
        ax1 = fmaf(wd, v3.x, ax1); ay1 = fmaf(wd, v3.y, ay1);
        ax2 = fmaf(we, v4.x, ax2); ay2 = fmaf(we, v4.y, ay2);
        ax2 = fmaf(wf, v5.x, ax2); ay2 = fmaf(wf, v5.y, ay2);
        ax2 = fmaf(wg, v6.x, ax2); ay2 = fmaf(wg, v6.y, ay2);
        ax2 = fmaf(wh, v7.x, ax2); ay2 = fmaf(wh, v7.y, ay2);
        j1 += 4; j2 += 4;
    }
    // 4 edges in flight tail
    while (j1 + 1 < e1 && j2 + 1 < e2) {
        edge8(csrA1, wk1, h16, j1,     f2, ax1, ay1);
        edge8(csrA1, wk1, h16, j1 + 1, f2, ax1, ay1);
        edge8(csrA2, wk2, h16, j2,     f2, ax2, ay2);
        edge8(csrA2, wk2, h16, j2 + 1, f2, ax2, ay2);
        j1 += 2; j2 += 2;
    }
    // drain remainders
    seg8(j1, e1, csrA1, wk1, h16, f2, ax1, ay1);
    seg8(j2, e2, csrA2, wk2, h16, f2, ax2, ay2);

    float ax = ax1 + ax2, ay = ay1 + ay2;
    int o = n * 8 + f2;
    if (SIG) {
        float2 r;
        r.x = 1.f / (1.f + expf(-2.f * ax));
        r.y = 1.f / (1.f + expf(-2.f * ay));
        ((float2*)hout)[o] = r;
    } else {
        float2 b = h0[o];
        ((__half2*)hout)[o] = __floats2half2_rn(ax + b.x, ay + b.y);
    }
}

// ---------------- fallback (atomic push path, needs only 6.4 MB ws) ----------------
__global__ __launch_bounds__(256) void scatter_layer(
    const int* __restrict__ src, const int* __restrict__ dst,
    const float* __restrict__ wt, const float* __restrict__ lw,
    const float* __restrict__ h, float* __restrict__ acc)
{
    long t = (long)blockIdx.x * blockDim.x + threadIdx.x;
    int e = (int)(t >> 4);
    if (e >= NEDGES) return;
    int f = (int)(t & 15);
    float w = wt[e] * lw[e];
    atomicAdd(&acc[dst[e] * NFEAT + f], w * h[src[e] * NFEAT + f]);
}
__global__ __launch_bounds__(256) void sigmoid_inplace(float* __restrict__ out, int n)
{
    int i = blockIdx.x * blockDim.x + threadIdx.x;
    if (i < n) out[i] = 1.f / (1.f + expf(-2.f * out[i]));
}

// ---------------- launch ----------------
extern "C" void kernel_launch(void* const* d_in, const int* in_sizes, int n_in,
                              void* d_out, int out_size, void* d_ws, size_t ws_size,
                              hipStream_t stream)
{
    const float* h0 = (const float*)d_in[0];
    const int*   ei = (const int*)d_in[1];     // int32 (JAX x64 off)
    const float* wt = (const float*)d_in[2];
    const float* lw = (const float*)d_in[3];

    const int* src = ei;
    const int* dst = ei + NEDGES;

    // workspace layout (bytes)
    const size_t off_cnt   = 0;                                 // int[125*250]
    const size_t off_tot   = 125056;
    const size_t off_bb    = 126080;
    const size_t off_offs1 = 127104;                            // int[100001]
    const size_t off_offs2 = off_offs1 + 400128;
    const size_t off_csrA  = off_offs2 + 400128;                // u32[2*EH]   12.8 MB
    const size_t off_w     = off_csrA + (size_t)2 * EH * 4;     // f16[8*EH]   25.6 MB
    const size_t off_bins  = off_w + (size_t)8 * EH * 2;        // u32[3*EH]   19.2 MB
    const size_t need      = off_bins + (size_t)3 * EH * 4;     // ~58.5 MB

    if (ws_size < need) {
        const size_t hbytes = (size_t)NNODES * NFEAT * sizeof(float);
        float* hw = (float*)d_ws;
        float* ho = (float*)d_out;
        dim3 blk(256), grd(((long)NEDGES * 16 + 255) / 256);
        hipMemcpyAsync(hw, h0, hbytes, hipMemcpyDeviceToDevice, stream);
        scatter_layer<<<grd, blk, 0, stream>>>(src, dst, wt, lw + 0L * NEDGES, h0, hw);
        hipMemcpyAsync(ho, h0, hbytes, hipMemcpyDeviceToDevice, stream);
        scatter_layer<<<grd, blk, 0, stream>>>(src, dst, wt, lw + 1L * NEDGES, hw, ho);
        hipMemcpyAsync(hw, h0, hbytes, hipMemcpyDeviceToDevice, stream);
        scatter_layer<<<grd, blk, 0, stream>>>(src, dst, wt, lw + 2L * NEDGES, ho, hw);
        hipMemsetAsync(ho, 0, hbytes, stream);
        scatter_layer<<<grd, blk, 0, stream>>>(src, dst, wt, lw + 3L * NEDGES, hw, ho);
        int n = NNODES * NFEAT;
        sigmoid_inplace<<<(n + 255) / 256, 256, 0, stream>>>(ho, n);
        return;
    }

    char* ws = (char*)d_ws;
    int*            cnt   = (int*)(ws + off_cnt);
    int*            tot   = (int*)(ws + off_tot);
    int*            bb    = (int*)(ws + off_bb);
    int*            offs1 = (int*)(ws + off_offs1);
    int*            offs2 = (int*)(ws + off_offs2);
    unsigned int*   csrA1 = (unsigned int*)(ws + off_csrA);
    unsigned int*   csrA2 = csrA1 + EH;
    unsigned short* wbase = (unsigned short*)(ws + off_w);
    unsigned short* w0_1 = wbase + 0L * EH; unsigned short* w1_1 = wbase + 1L * EH;
    unsigned short* w2_1 = wbase + 2L * EH; unsigned short* w3_1 = wbase + 3L * EH;
    unsigned short* w0_2 = wbase + 4L * EH; unsigned short* w1_2 = wbase + 5L * EH;
    unsigned short* w2_2 = wbase + 6L * EH; unsigned short* w3_2 = wbase + 7L * EH;
    unsigned int*   binsE = (unsigned int*)(ws + off_bins);
    // aliases over the dead bins region (alive only after both bucket_csr calls)
    __half2*        hb0   = (__half2*)(ws + off_bins);                                  // f16(h0)
    __half2*        hbA   = (__half2*)(ws + off_bins + 1 * (size_t)NNODES * NFEAT * 2); // ping
    __half2*        hbB   = (__half2*)(ws + off_bins + 2 * (size_t)NNODES * NFEAT * 2); // pong
    float*          hout  = (float*)d_out;

    // ---- build: two independent halves ----
    // half 1
    hist_chunk  <<<NCH, 1024, 0, stream>>>(dst, 0, cnt);
    scan_chunks <<<NB,   256, 0, stream>>>(cnt, tot);
    scan_tot    <<<1,    256, 0, stream>>>(tot, bb);
    scatter_bins<<<NCH, 1024, 0, stream>>>(src, dst, wt, lw, 0, cnt, bb, binsE);
    bucket_csr  <<<NB,   512, 0, stream>>>(bb, binsE, csrA1, w0_1, w1_1, w2_1, w3_1, offs1);
    // half 2
    hist_chunk  <<<NCH, 1024, 0, stream>>>(dst, EH, cnt);
    scan_chunks <<<NB,   256, 0, stream>>>(cnt, tot);
    scan_tot    <<<1,    256, 0, stream>>>(tot, bb);
    scatter_bins<<<NCH, 1024, 0, stream>>>(src, dst, wt, lw, EH, cnt, bb, binsE);
    bucket_csr  <<<NB,   512, 0, stream>>>(bb, binsE, csrA2, w0_2, w1_2, w2_2, w3_2, offs2);

    // ---- convert h0 to f16 (bins region now dead) ----
    int n2 = NNODES * NFEAT / 2;
    conv16<<<(n2 + 255) / 256, 256, 0, stream>>>((const float2*)h0, (__half2*)hb0, n2);

    // ---- 4 pull layers (8 lanes/node, half2 gathers) ----
    dim3 blk(256), grd((NNODES * 8) / 256);
    pull8<false><<<grd, blk, 0, stream>>>(offs1, offs2, csrA1, csrA2, w0_1, w0_2, hb0, (const float2*)h0, hbA);
    pull8<false><<<grd, blk, 0, stream>>>(offs1, offs2, csrA1, csrA2, w1_1, w1_2, hbA, (const float2*)h0, hbB);
    pull8<false><<<grd, blk, 0, stream>>>(offs1, offs2, csrA1, csrA2, w2_1, w2_2, hbB, (const float2*)h0, hbA);
    pull8<true ><<<grd, blk, 0, stream>>>(offs1, offs2, csrA1, csrA2, w3_1, w3_2, hbA, (const float2*)h0, hout);
}

// Round 15
// 255.986 us; speedup vs baseline: 1.0877x; 1.0877x over previous
//
#include <hip/hip_runtime.h>
#include <hip/hip_fp16.h>

#define NNODES   100000
#define NFEAT    16
#define NEDGES   3200000
#define EH       1600000     // edges per half
#define NB       250         // dst buckets
#define NODES_PB 400         // 250*400 = 100000
#define NCH      125         // chunks per half
#define CHK      12800       // 125*12800 = 1600000
#define CAP      7168        // per-bucket-half capacity (mean 6400, sigma~80 -> +9.6s)
#define N8       (NNODES * 8)   // half2 elements per h-plane

// ---------- K1: per-chunk bucket histogram over one half ----------
__global__ __launch_bounds__(1024) void hist_chunk(
    const int* __restrict__ dst, int ebase, int* __restrict__ cnt /*[NCH][NB]*/)
{
    __shared__ int h[NB];
    int c = blockIdx.x;
    for (int i = threadIdx.x; i < NB; i += 1024) h[i] = 0;
    __syncthreads();
    int base = ebase + c * CHK;
    for (int i = threadIdx.x; i < CHK; i += 1024) {
        int d = dst[base + i];
        atomicAdd(&h[d / NODES_PB], 1);
    }
    __syncthreads();
    for (int i = threadIdx.x; i < NB; i += 1024) cnt[c * NB + i] = h[i];
}

// ---------- K2: per-bucket exclusive scan over chunks ----------
__global__ __launch_bounds__(256) void scan_chunks(
    int* __restrict__ cnt, int* __restrict__ tot)
{
    __shared__ int x[256];
    int b = blockIdx.x, t = threadIdx.x;
    int v = (t < NCH) ? cnt[t * NB + b] : 0;
    x[t] = v;
    __syncthreads();
    for (int off = 1; off < 256; off <<= 1) {
        int y = (t >= off) ? x[t - off] : 0;
        __syncthreads();
        x[t] += y;
        __syncthreads();
    }
    if (t < NCH) cnt[t * NB + b] = x[t] - v;
    if (t == NCH - 1) tot[b] = x[t];
}

// ---------- K3: exclusive scan of bucket totals -> bb[NB+1] ----------
__global__ __launch_bounds__(256) void scan_tot(
    const int* __restrict__ tot, int* __restrict__ bb)
{
    __shared__ int x[256];
    int t = threadIdx.x;
    int v = (t < NB) ? tot[t] : 0;
    x[t] = v;
    __syncthreads();
    for (int off = 1; off < 256; off <<= 1) {
        int y = (t >= off) ? x[t - off] : 0;
        __syncthreads();
        x[t] += y;
        __syncthreads();
    }
    if (t < NB) bb[t] = x[t] - v;
    if (t == NB - 1) bb[NB] = x[t];
}

// ---------- K4: scatter edges of one half into bucket-major AoS slots ----------
// entry = 3 dwords: {src | dl<<17, half2(w0,w1), half2(w2,w3)}
__global__ __launch_bounds__(1024) void scatter_bins(
    const int*   __restrict__ src,
    const int*   __restrict__ dst,
    const float* __restrict__ wt,
    const float* __restrict__ lw,
    int ebase,
    const int*   __restrict__ cnt,
    const int*   __restrict__ bb,
    unsigned int* __restrict__ binsE)
{
    __shared__ int cur[NB];
    int c = blockIdx.x;
    for (int i = threadIdx.x; i < NB; i += 1024)
        cur[i] = bb[i] + cnt[c * NB + i];
    __syncthreads();
    int base = ebase + c * CHK;
    for (int i = threadIdx.x; i < CHK; i += 1024) {
        int e = base + i;
        int d = dst[e];
        int b  = d / NODES_PB;
        int dl = d - b * NODES_PB;
        float w = wt[e];
        __half2 w01 = __floats2half2_rn(w * lw[e],              w * lw[NEDGES + e]);
        __half2 w23 = __floats2half2_rn(w * lw[2 * NEDGES + e], w * lw[3 * NEDGES + e]);
        int slot = atomicAdd(&cur[b], 1);
        unsigned int* p = binsE + 3u * (unsigned int)slot;
        p[0] = (unsigned int)src[e] | ((unsigned int)dl << 17);
        p[1] = *(const unsigned int*)&w01;
        p[2] = *(const unsigned int*)&w23;
    }
}

// ---------- K5: per-bucket node sort, permutation in LDS, sequential flushes ----------
__global__ __launch_bounds__(512) void bucket_csr(
    const int*          __restrict__ bb,
    const unsigned int* __restrict__ binsE,
    unsigned int*       __restrict__ csrA,
    unsigned short*     __restrict__ w0,    // f16 bit patterns
    unsigned short*     __restrict__ w1,
    unsigned short*     __restrict__ w2,
    unsigned short*     __restrict__ w3,
    int*                __restrict__ offs)
{
    __shared__ unsigned int   regA[CAP];    // P1-P2b: sA ; P3-P4: {w0,w1} u16 planes
    __shared__ unsigned int   regC[CAP];    // P2-P2b: inv u16 ; P3-P4: {w2,w3} u16 planes
    __shared__ unsigned short pi[CAP];      // edge -> slot
    __shared__ int hist[NODES_PB];
    __shared__ int cur[NODES_PB];
    __shared__ int sc[512];                 // total ~75 KiB -> 2 blocks/CU
    int b  = blockIdx.x, t = threadIdx.x;
    int e0 = bb[b];
    int cnt = bb[b + 1] - e0;
    if (cnt > CAP) cnt = CAP;               // statistically impossible; guards corruption

    for (int i = t; i < NODES_PB; i += 512) hist[i] = 0;
    __syncthreads();
    // P1: stage word0 + node histogram
    for (int i = t; i < cnt; i += 512) {
        unsigned int a = binsE[3u * (unsigned int)(e0 + i)];
        regA[i] = a;
        atomicAdd(&hist[a >> 17], 1);
    }
    __syncthreads();
    // exclusive scan of 400 node counts
    int v = (t < NODES_PB) ? hist[t] : 0;
    sc[t] = v;
    __syncthreads();
    for (int off = 1; off < 512; off <<= 1) {
        int y = (t >= off) ? sc[t - off] : 0;
        __syncthreads();
        sc[t] += y;
        __syncthreads();
    }
    if (t < NODES_PB) {
        int excl = sc[t] - v;
        cur[t] = excl;
        offs[b * NODES_PB + t] = e0 + excl;
    }
    if (b == 0 && t == 0) offs[NNODES] = EH;
    __syncthreads();
    // P2: assign slots; build pi (edge->slot) and inv (slot->edge) in LDS
    unsigned short* inv = (unsigned short*)regC;
    for (int i = t; i < cnt; i += 512) {
        unsigned int a = regA[i];
        int slot = atomicAdd(&cur[a >> 17], 1);
        pi[i]  = (unsigned short)slot;
        inv[slot] = (unsigned short)i;
    }
    __syncthreads();
    // P2b: flush csrA SEQUENTIALLY (gather via inv)
    for (int s = t; s < cnt; s += 512) {
        csrA[e0 + s] = regA[inv[s]] & 0x1FFFFu;
    }
    __syncthreads();
    // P3: read weight words once; scatter f16 halves into LDS planes at pi[i]
    unsigned short* wA0 = (unsigned short*)regA;         // overwrites dead sA
    unsigned short* wA1 = wA0 + CAP;
    unsigned short* wC2 = (unsigned short*)regC;         // overwrites dead inv
    unsigned short* wC3 = wC2 + CAP;
    for (int i = t; i < cnt; i += 512) {
        unsigned int u01 = binsE[3u * (unsigned int)(e0 + i) + 1];
        unsigned int u23 = binsE[3u * (unsigned int)(e0 + i) + 2];
        int s = pi[i];
        wA0[s] = (unsigned short)(u01 & 0xFFFFu);
        wA1[s] = (unsigned short)(u01 >> 16);
        wC2[s] = (unsigned short)(u23 & 0xFFFFu);
        wC3[s] = (unsigned short)(u23 >> 16);
    }
    __syncthreads();
    // P4: flush all four planes SEQUENTIALLY
    for (int s = t; s < cnt; s += 512) {
        w0[e0 + s] = wA0[s];
        w1[e0 + s] = wA1[s];
        w2[e0 + s] = wC2[s];
        w3[e0 + s] = wC3[s];
    }
}

// ---------- K5b: convert h0 (f32) -> f16 table ----------
__global__ __launch_bounds__(256) void conv16(
    const float2* __restrict__ in, __half2* __restrict__ out, int n2)
{
    int i = blockIdx.x * 256 + threadIdx.x;
    if (i < n2) {
        float2 v = in[i];
        out[i] = __floats2half2_rn(v.x, v.y);
    }
}

// ---------- K6: quarter-pull — node split 4 ways, 8 lanes/quarter, f16 partials ----------
// thread map: n = t>>5, grp = (t>>3)&3, f2 = t&7.  One 64-lane wave = 2 nodes.
// grp 0/1: halves of csrA1 list; grp 2/3: halves of csrA2 list.
__global__ __launch_bounds__(256) void pullq(
    const int*            __restrict__ offs1,
    const int*            __restrict__ offs2,
    const unsigned int*   __restrict__ csrA1,
    const unsigned int*   __restrict__ csrA2,
    const unsigned short* __restrict__ wk1,
    const unsigned short* __restrict__ wk2,
    const __half2*        __restrict__ h16,     // [N8]
    __half2*              __restrict__ partial) // [4][N8]
{
    int t = blockIdx.x * 256 + threadIdx.x;
    int n = t >> 5;
    if (n >= NNODES) return;
    int grp = (t >> 3) & 3;
    int f2  = t & 7;

    int j01 = offs1[n], e1 = offs1[n + 1];
    int j02 = offs2[n], e2 = offs2[n + 1];
    int m1 = (j01 + e1) >> 1;
    int m2 = (j02 + e2) >> 1;

    const unsigned int*   A;
    const unsigned short* W;
    int js, je;
    if (grp < 2) {
        A = csrA1; W = wk1;
        js = (grp == 0) ? j01 : m1;
        je = (grp == 0) ? m1  : e1;
    } else {
        A = csrA2; W = wk2;
        js = (grp == 2) ? j02 : m2;
        je = (grp == 2) ? m2  : e2;
    }

    float ax = 0.f, ay = 0.f;
    int j = js;
    // 4 edges in flight per lane (x8 groups/wave = 32 outstanding per wave)
    for (; j + 3 < je; j += 4) {
        unsigned int s0 = A[j],     s1 = A[j + 1];
        unsigned int s2 = A[j + 2], s3 = A[j + 3];
        float w0 = __half2float(__ushort_as_half(W[j]));
        float w1 = __half2float(__ushort_as_half(W[j + 1]));
        float w2 = __half2float(__ushort_as_half(W[j + 2]));
        float w3 = __half2float(__ushort_as_half(W[j + 3]));
        float2 v0 = __half22float2(h16[s0 * 8 + f2]);
        float2 v1 = __half22float2(h16[s1 * 8 + f2]);
        float2 v2 = __half22float2(h16[s2 * 8 + f2]);
        float2 v3 = __half22float2(h16[s3 * 8 + f2]);
        ax = fmaf(w0, v0.x, ax); ay = fmaf(w0, v0.y, ay);
        ax = fmaf(w1, v1.x, ax); ay = fmaf(w1, v1.y, ay);
        ax = fmaf(w2, v2.x, ax); ay = fmaf(w2, v2.y, ay);
        ax = fmaf(w3, v3.x, ax); ay = fmaf(w3, v3.y, ay);
    }
    for (; j < je; ++j) {
        unsigned int s = A[j];
        float w = __half2float(__ushort_as_half(W[j]));
        float2 v = __half22float2(h16[s * 8 + f2]);
        ax = fmaf(w, v.x, ax); ay = fmaf(w, v.y, ay);
    }

    partial[grp * N8 + n * 8 + f2] = __floats2half2_rn(ax, ay);
}

// ---------- K7: combine partials (+h0 residual or sigmoid) ----------
template<bool SIG>
__global__ __launch_bounds__(256) void combine(
    const __half2* __restrict__ partial,  // [4][N8]
    const float2*  __restrict__ h0,       // residual (ignored if SIG)
    void*          __restrict__ hout)
{
    int i = blockIdx.x * 256 + threadIdx.x;
    if (i >= N8) return;
    float2 p0 = __half22float2(partial[0 * N8 + i]);
    float2 p1 = __half22float2(partial[1 * N8 + i]);
    float2 p2 = __half22float2(partial[2 * N8 + i]);
    float2 p3 = __half22float2(partial[3 * N8 + i]);
    float sx = (p0.x + p1.x) + (p2.x + p3.x);
    float sy = (p0.y + p1.y) + (p2.y + p3.y);
    if (SIG) {
        float2 r;
        r.x = 1.f / (1.f + expf(-2.f * sx));
        r.y = 1.f / (1.f + expf(-2.f * sy));
        ((float2*)hout)[i] = r;
    } else {
        float2 b = h0[i];
        ((__half2*)hout)[i] = __floats2half2_rn(sx + b.x, sy + b.y);
    }
}

// ---------------- fallback (atomic push path, needs only 6.4 MB ws) ----------------
__global__ __launch_bounds__(256) void scatter_layer(
    const int* __restrict__ src, const int* __restrict__ dst,
    const float* __restrict__ wt, const float* __restrict__ lw,
    const float* __restrict__ h, float* __restrict__ acc)
{
    long t = (long)blockIdx.x * blockDim.x + threadIdx.x;
    int e = (int)(t >> 4);
    if (e >= NEDGES) return;
    int f = (int)(t & 15);
    float w = wt[e] * lw[e];
    atomicAdd(&acc[dst[e] * NFEAT + f], w * h[src[e] * NFEAT + f]);
}
__global__ __launch_bounds__(256) void sigmoid_inplace(float* __restrict__ out, int n)
{
    int i = blockIdx.x * blockDim.x + threadIdx.x;
    if (i < n) out[i] = 1.f / (1.f + expf(-2.f * out[i]));
}

// ---------------- launch ----------------
extern "C" void kernel_launch(void* const* d_in, const int* in_sizes, int n_in,
                              void* d_out, int out_size, void* d_ws, size_t ws_size,
                              hipStream_t stream)
{
    const float* h0 = (const float*)d_in[0];
    const int*   ei = (const int*)d_in[1];     // int32 (JAX x64 off)
    const float* wt = (const float*)d_in[2];
    const float* lw = (const float*)d_in[3];

    const int* src = ei;
    const int* dst = ei + NEDGES;

    // workspace layout (bytes)
    const size_t off_cnt   = 0;                                 // int[125*250]
    const size_t off_tot   = 125056;
    const size_t off_bb    = 126080;
    const size_t off_offs1 = 127104;                            // int[100001]
    const size_t off_offs2 = off_offs1 + 400128;
    const size_t off_csrA  = off_offs2 + 400128;                // u32[2*EH]   12.8 MB
    const size_t off_w     = off_csrA + (size_t)2 * EH * 4;     // f16[8*EH]   25.6 MB
    const size_t off_bins  = off_w + (size_t)8 * EH * 2;        // u32[3*EH]   19.2 MB
    const size_t need      = off_bins + (size_t)3 * EH * 4;     // ~58.5 MB

    if (ws_size < need) {
        const size_t hbytes = (size_t)NNODES * NFEAT * sizeof(float);
        float* hw = (float*)d_ws;
        float* ho = (float*)d_out;
        dim3 blk(256), grd(((long)NEDGES * 16 + 255) / 256);
        hipMemcpyAsync(hw, h0, hbytes, hipMemcpyDeviceToDevice, stream);
        scatter_layer<<<grd, blk, 0, stream>>>(src, dst, wt, lw + 0L * NEDGES, h0, hw);
        hipMemcpyAsync(ho, h0, hbytes, hipMemcpyDeviceToDevice, stream);
        scatter_layer<<<grd, blk, 0, stream>>>(src, dst, wt, lw + 1L * NEDGES, hw, ho);
        hipMemcpyAsync(hw, h0, hbytes, hipMemcpyDeviceToDevice, stream);
        scatter_layer<<<grd, blk, 0, stream>>>(src, dst, wt, lw + 2L * NEDGES, ho, hw);
        hipMemsetAsync(ho, 0, hbytes, stream);
        scatter_layer<<<grd, blk, 0, stream>>>(src, dst, wt, lw + 3L * NEDGES, hw, ho);
        int n = NNODES * NFEAT;
        sigmoid_inplace<<<(n + 255) / 256, 256, 0, stream>>>(ho, n);
        return;
    }

    char* ws = (char*)d_ws;
    int*            cnt   = (int*)(ws + off_cnt);
    int*            tot   = (int*)(ws + off_tot);
    int*            bb    = (int*)(ws + off_bb);
    int*            offs1 = (int*)(ws + off_offs1);
    int*            offs2 = (int*)(ws + off_offs2);
    unsigned int*   csrA1 = (unsigned int*)(ws + off_csrA);
    unsigned int*   csrA2 = csrA1 + EH;
    unsigned short* wbase = (unsigned short*)(ws + off_w);
    unsigned short* w0_1 = wbase + 0L * EH; unsigned short* w1_1 = wbase + 1L * EH;
    unsigned short* w2_1 = wbase + 2L * EH; unsigned short* w3_1 = wbase + 3L * EH;
    unsigned short* w0_2 = wbase + 4L * EH; unsigned short* w1_2 = wbase + 5L * EH;
    unsigned short* w2_2 = wbase + 6L * EH; unsigned short* w3_2 = wbase + 7L * EH;
    unsigned int*   binsE = (unsigned int*)(ws + off_bins);
    // aliases over the dead bins region (alive only after both bucket_csr calls):
    // [hb0: 3.2MB][partials p0..p3: 12.8MB][hbA: 3.2MB]  = 19.2MB exactly
    const size_t HB = (size_t)NNODES * NFEAT * 2;   // 3.2 MB
    __half2* hb0      = (__half2*)(ws + off_bins);
    __half2* partials = (__half2*)(ws + off_bins + HB);
    __half2* hbA      = (__half2*)(ws + off_bins + 5 * HB);
    __half2* hbB      = (__half2*)d_out;            // f16 scratch inside d_out
    float*   hout     = (float*)d_out;

    // ---- build: two independent halves ----
    // half 1
    hist_chunk  <<<NCH, 1024, 0, stream>>>(dst, 0, cnt);
    scan_chunks <<<NB,   256, 0, stream>>>(cnt, tot);
    scan_tot    <<<1,    256, 0, stream>>>(tot, bb);
    scatter_bins<<<NCH, 1024, 0, stream>>>(src, dst, wt, lw, 0, cnt, bb, binsE);
    bucket_csr  <<<NB,   512, 0, stream>>>(bb, binsE, csrA1, w0_1, w1_1, w2_1, w3_1, offs1);
    // half 2
    hist_chunk  <<<NCH, 1024, 0, stream>>>(dst, EH, cnt);
    scan_chunks <<<NB,   256, 0, stream>>>(cnt, tot);
    scan_tot    <<<1,    256, 0, stream>>>(tot, bb);
    scatter_bins<<<NCH, 1024, 0, stream>>>(src, dst, wt, lw, EH, cnt, bb, binsE);
    bucket_csr  <<<NB,   512, 0, stream>>>(bb, binsE, csrA2, w0_2, w1_2, w2_2, w3_2, offs2);

    // ---- convert h0 to f16 (bins region now dead) ----
    conv16<<<(N8 + 255) / 256, 256, 0, stream>>>((const float2*)h0, hb0, N8);

    // ---- 4 layers: quarter-pull + combine ----
    dim3 blk(256), grdP((NNODES * 32) / 256), grdC((N8 + 255) / 256);
    const float2* h0f2 = (const float2*)h0;
    // L0: hb0 -> hbA
    pullq<<<grdP, blk, 0, stream>>>(offs1, offs2, csrA1, csrA2, w0_1, w0_2, hb0, partials);
    combine<false><<<grdC, blk, 0, stream>>>(partials, h0f2, hbA);
    // L1: hbA -> hbB
    pullq<<<grdP, blk, 0, stream>>>(offs1, offs2, csrA1, csrA2, w1_1, w1_2, hbA, partials);
    combine<false><<<grdC, blk, 0, stream>>>(partials, h0f2, hbB);
    // L2: hbB -> hbA
    pullq<<<grdP, blk, 0, stream>>>(offs1, offs2, csrA1, csrA2, w2_1, w2_2, hbB, partials);
    combine<false><<<grdC, blk, 0, stream>>>(partials, h0f2, hbA);
    // L3: hbA -> sigmoid f32 out
    pullq<<<grdP, blk, 0, stream>>>(offs1, offs2, csrA1, csrA2, w3_1, w3_2, hbA, partials);
    combine<true ><<<grdC, blk, 0, stream>>>(partials, h0f2, hout);
}

// Round 16
// 245.239 us; speedup vs baseline: 1.1353x; 1.0438x over previous
//
#include <hip/hip_runtime.h>
#include <hip/hip_fp16.h>

#define NNODES   100000
#define NFEAT    16
#define NEDGES   3200000
#define EH       1600000     // edges per half
#define NB       250         // dst buckets
#define NODES_PB 400         // 250*400 = 100000
#define NCH      500         // chunks per half
#define CHK      3200        // 500*3200 = 1600000
#define CAP      7168        // per-bucket-half capacity (mean 6400, sigma~80 -> +9.6s)
#define N8       (NNODES * 8)   // half2 elements per h-plane

// ---------- K1: per-chunk bucket histogram over one half ----------
__global__ __launch_bounds__(256) void hist_chunk(
    const int* __restrict__ dst, int ebase, int* __restrict__ cnt /*[NCH][NB]*/)
{
    __shared__ int h[NB];
    int c = blockIdx.x;
    for (int i = threadIdx.x; i < NB; i += 256) h[i] = 0;
    __syncthreads();
    int base = ebase + c * CHK;
    for (int i = threadIdx.x; i < CHK; i += 256) {
        int d = dst[base + i];
        atomicAdd(&h[d / NODES_PB], 1);
    }
    __syncthreads();
    for (int i = threadIdx.x; i < NB; i += 256) cnt[c * NB + i] = h[i];
}

// ---------- K2: per-bucket exclusive scan over chunks (512-wide) ----------
__global__ __launch_bounds__(512) void scan_chunks(
    int* __restrict__ cnt, int* __restrict__ tot)
{
    __shared__ int x[512];
    int b = blockIdx.x, t = threadIdx.x;
    int v = (t < NCH) ? cnt[t * NB + b] : 0;
    x[t] = v;
    __syncthreads();
    for (int off = 1; off < 512; off <<= 1) {
        int y = (t >= off) ? x[t - off] : 0;
        __syncthreads();
        x[t] += y;
        __syncthreads();
    }
    if (t < NCH) cnt[t * NB + b] = x[t] - v;
    if (t == NCH - 1) tot[b] = x[t];
}

// ---------- K3: exclusive scan of bucket totals -> bb[NB+1] ----------
__global__ __launch_bounds__(256) void scan_tot(
    const int* __restrict__ tot, int* __restrict__ bb)
{
    __shared__ int x[256];
    int t = threadIdx.x;
    int v = (t < NB) ? tot[t] : 0;
    x[t] = v;
    __syncthreads();
    for (int off = 1; off < 256; off <<= 1) {
        int y = (t >= off) ? x[t - off] : 0;
        __syncthreads();
        x[t] += y;
        __syncthreads();
    }
    if (t < NB) bb[t] = x[t] - v;
    if (t == NB - 1) bb[NB] = x[t];
}

// ---------- K4: scatter edges of one half into bucket-major AoS slots ----------
// entry = 3 dwords: {src | dl<<17, half2(w0,w1), half2(w2,w3)}
__global__ __launch_bounds__(256) void scatter_bins(
    const int*   __restrict__ src,
    const int*   __restrict__ dst,
    const float* __restrict__ wt,
    const float* __restrict__ lw,
    int ebase,
    const int*   __restrict__ cnt,
    const int*   __restrict__ bb,
    unsigned int* __restrict__ binsE)
{
    __shared__ int cur[NB];
    int c = blockIdx.x;
    for (int i = threadIdx.x; i < NB; i += 256)
        cur[i] = bb[i] + cnt[c * NB + i];
    __syncthreads();
    int base = ebase + c * CHK;
    for (int i = threadIdx.x; i < CHK; i += 256) {
        int e = base + i;
        int d = dst[e];
        int b  = d / NODES_PB;
        int dl = d - b * NODES_PB;
        float w = wt[e];
        __half2 w01 = __floats2half2_rn(w * lw[e],              w * lw[NEDGES + e]);
        __half2 w23 = __floats2half2_rn(w * lw[2 * NEDGES + e], w * lw[3 * NEDGES + e]);
        int slot = atomicAdd(&cur[b], 1);
        unsigned int* p = binsE + 3u * (unsigned int)slot;
        p[0] = (unsigned int)src[e] | ((unsigned int)dl << 17);
        p[1] = *(const unsigned int*)&w01;
        p[2] = *(const unsigned int*)&w23;
    }
}

// ---------- K5: per-bucket node sort, permutation in LDS, sequential flushes ----------
__global__ __launch_bounds__(512) void bucket_csr(
    const int*          __restrict__ bb,
    const unsigned int* __restrict__ binsE,
    unsigned int*       __restrict__ csrA,
    unsigned short*     __restrict__ w0,    // f16 bit patterns
    unsigned short*     __restrict__ w1,
    unsigned short*     __restrict__ w2,
    unsigned short*     __restrict__ w3,
    int*                __restrict__ offs)
{
    __shared__ unsigned int   regA[CAP];    // P1-P2b: sA ; P3-P4: {w0,w1} u16 planes
    __shared__ unsigned int   regC[CAP];    // P2-P2b: inv u16 ; P3-P4: {w2,w3} u16 planes
    __shared__ unsigned short pi[CAP];      // edge -> slot
    __shared__ int hist[NODES_PB];
    __shared__ int cur[NODES_PB];
    __shared__ int sc[512];                 // total ~75 KiB -> 2 blocks/CU
    int b  = blockIdx.x, t = threadIdx.x;
    int e0 = bb[b];
    int cnt = bb[b + 1] - e0;
    if (cnt > CAP) cnt = CAP;               // statistically impossible; guards corruption

    for (int i = t; i < NODES_PB; i += 512) hist[i] = 0;
    __syncthreads();
    // P1: stage word0 + node histogram
    for (int i = t; i < cnt; i += 512) {
        unsigned int a = binsE[3u * (unsigned int)(e0 + i)];
        regA[i] = a;
        atomicAdd(&hist[a >> 17], 1);
    }
    __syncthreads();
    // exclusive scan of 400 node counts
    int v = (t < NODES_PB) ? hist[t] : 0;
    sc[t] = v;
    __syncthreads();
    for (int off = 1; off < 512; off <<= 1) {
        int y = (t >= off) ? sc[t - off] : 0;
        __syncthreads();
        sc[t] += y;
        __syncthreads();
    }
    if (t < NODES_PB) {
        int excl = sc[t] - v;
        cur[t] = excl;
        offs[b * NODES_PB + t] = e0 + excl;
    }
    if (b == 0 && t == 0) offs[NNODES] = EH;
    __syncthreads();
    // P2: assign slots; build pi (edge->slot) and inv (slot->edge) in LDS
    unsigned short* inv = (unsigned short*)regC;
    for (int i = t; i < cnt; i += 512) {
        unsigned int a = regA[i];
        int slot = atomicAdd(&cur[a >> 17], 1);
        pi[i]  = (unsigned short)slot;
        inv[slot] = (unsigned short)i;
    }
    __syncthreads();
    // P2b: flush csrA SEQUENTIALLY (gather via inv)
    for (int s = t; s < cnt; s += 512) {
        csrA[e0 + s] = regA[inv[s]] & 0x1FFFFu;
    }
    __syncthreads();
    // P3: read weight words once; scatter f16 halves into LDS planes at pi[i]
    unsigned short* wA0 = (unsigned short*)regA;         // overwrites dead sA
    unsigned short* wA1 = wA0 + CAP;
    unsigned short* wC2 = (unsigned short*)regC;         // overwrites dead inv
    unsigned short* wC3 = wC2 + CAP;
    for (int i = t; i < cnt; i += 512) {
        unsigned int u01 = binsE[3u * (unsigned int)(e0 + i) + 1];
        unsigned int u23 = binsE[3u * (unsigned int)(e0 + i) + 2];
        int s = pi[i];
        wA0[s] = (unsigned short)(u01 & 0xFFFFu);
        wA1[s] = (unsigned short)(u01 >> 16);
        wC2[s] = (unsigned short)(u23 & 0xFFFFu);
        wC3[s] = (unsigned short)(u23 >> 16);
    }
    __syncthreads();
    // P4: flush all four planes SEQUENTIALLY
    for (int s = t; s < cnt; s += 512) {
        w0[e0 + s] = wA0[s];
        w1[e0 + s] = wA1[s];
        w2[e0 + s] = wC2[s];
        w3[e0 + s] = wC3[s];
    }
}

// ---------- K5b: convert h0 (f32) -> f16 table ----------
__global__ __launch_bounds__(256) void conv16(
    const float2* __restrict__ in, __half2* __restrict__ out, int n2)
{
    int i = blockIdx.x * 256 + threadIdx.x;
    if (i < n2) {
        float2 v = in[i];
        out[i] = __floats2half2_rn(v.x, v.y);
    }
}

// ---------- K6: pull with in-wave combine ----------
// thread map: n = t>>5, grp = (t>>3)&3, f2 = t&7.  One 64-lane wave = 2 nodes;
// the 4 quarter-groups of a node are lane bits 3-4 -> __shfl_xor(8/16) reduce.
template<bool SIG>
__global__ __launch_bounds__(256) void pullr(
    const int*            __restrict__ offs1,
    const int*            __restrict__ offs2,
    const unsigned int*   __restrict__ csrA1,
    const unsigned int*   __restrict__ csrA2,
    const unsigned short* __restrict__ wk1,
    const unsigned short* __restrict__ wk2,
    const __half2*        __restrict__ h16,   // [N8]
    const float2*         __restrict__ h0,    // residual (unused if SIG)
    void*                 __restrict__ hout)
{
    int t = blockIdx.x * 256 + threadIdx.x;
    int n = t >> 5;
    if (n >= NNODES) return;
    int grp = (t >> 3) & 3;
    int f2  = t & 7;

    int j01 = offs1[n], e1 = offs1[n + 1];
    int j02 = offs2[n], e2 = offs2[n + 1];
    int m1 = (j01 + e1) >> 1;
    int m2 = (j02 + e2) >> 1;

    const unsigned int*   A;
    const unsigned short* W;
    int js, je;
    if (grp < 2) {
        A = csrA1; W = wk1;
        js = (grp == 0) ? j01 : m1;
        je = (grp == 0) ? m1  : e1;
    } else {
        A = csrA2; W = wk2;
        js = (grp == 2) ? j02 : m2;
        je = (grp == 2) ? m2  : e2;
    }

    float ax = 0.f, ay = 0.f;
    int j = js;
    for (; j + 3 < je; j += 4) {
        unsigned int s0 = A[j],     s1 = A[j + 1];
        unsigned int s2 = A[j + 2], s3 = A[j + 3];
        float w0 = __half2float(__ushort_as_half(W[j]));
        float w1 = __half2float(__ushort_as_half(W[j + 1]));
        float w2 = __half2float(__ushort_as_half(W[j + 2]));
        float w3 = __half2float(__ushort_as_half(W[j + 3]));
        float2 v0 = __half22float2(h16[s0 * 8 + f2]);
        float2 v1 = __half22float2(h16[s1 * 8 + f2]);
        float2 v2 = __half22float2(h16[s2 * 8 + f2]);
        float2 v3 = __half22float2(h16[s3 * 8 + f2]);
        ax = fmaf(w0, v0.x, ax); ay = fmaf(w0, v0.y, ay);
        ax = fmaf(w1, v1.x, ax); ay = fmaf(w1, v1.y, ay);
        ax = fmaf(w2, v2.x, ax); ay = fmaf(w2, v2.y, ay);
        ax = fmaf(w3, v3.x, ax); ay = fmaf(w3, v3.y, ay);
    }
    for (; j < je; ++j) {
        unsigned int s = A[j];
        float w = __half2float(__ushort_as_half(W[j]));
        float2 v = __half22float2(h16[s * 8 + f2]);
        ax = fmaf(w, v.x, ax); ay = fmaf(w, v.y, ay);
    }

    // reduce the 4 groups in-wave (f32)
    ax += __shfl_xor(ax, 8);  ay += __shfl_xor(ay, 8);
    ax += __shfl_xor(ax, 16); ay += __shfl_xor(ay, 16);

    if (grp == 0) {
        int o = n * 8 + f2;
        if (SIG) {
            float2 r;
            r.x = 1.f / (1.f + expf(-2.f * ax));
            r.y = 1.f / (1.f + expf(-2.f * ay));
            ((float2*)hout)[o] = r;
        } else {
            float2 b = h0[o];
            ((__half2*)hout)[o] = __floats2half2_rn(ax + b.x, ay + b.y);
        }
    }
}

// ---------------- fallback (atomic push path, needs only 6.4 MB ws) ----------------
__global__ __launch_bounds__(256) void scatter_layer(
    const int* __restrict__ src, const int* __restrict__ dst,
    const float* __restrict__ wt, const float* __restrict__ lw,
    const float* __restrict__ h, float* __restrict__ acc)
{
    long t = (long)blockIdx.x * blockDim.x + threadIdx.x;
    int e = (int)(t >> 4);
    if (e >= NEDGES) return;
    int f = (int)(t & 15);
    float w = wt[e] * lw[e];
    atomicAdd(&acc[dst[e] * NFEAT + f], w * h[src[e] * NFEAT + f]);
}
__global__ __launch_bounds__(256) void sigmoid_inplace(float* __restrict__ out, int n)
{
    int i = blockIdx.x * blockDim.x + threadIdx.x;
    if (i < n) out[i] = 1.f / (1.f + expf(-2.f * out[i]));
}

// ---------------- launch ----------------
extern "C" void kernel_launch(void* const* d_in, const int* in_sizes, int n_in,
                              void* d_out, int out_size, void* d_ws, size_t ws_size,
                              hipStream_t stream)
{
    const float* h0 = (const float*)d_in[0];
    const int*   ei = (const int*)d_in[1];     // int32 (JAX x64 off)
    const float* wt = (const float*)d_in[2];
    const float* lw = (const float*)d_in[3];

    const int* src = ei;
    const int* dst = ei + NEDGES;

    // workspace layout (bytes)
    const size_t off_cnt   = 0;                                 // int[500*250] = 500000
    const size_t off_tot   = 500224;
    const size_t off_bb    = 501248;
    const size_t off_offs1 = 502272;                            // int[100001]
    const size_t off_offs2 = off_offs1 + 400128;
    const size_t off_csrA  = off_offs2 + 400128;                // u32[2*EH]   12.8 MB
    const size_t off_w     = off_csrA + (size_t)2 * EH * 4;     // f16[8*EH]   25.6 MB
    const size_t off_bins  = off_w + (size_t)8 * EH * 2;        // u32[3*EH]   19.2 MB
    const size_t need      = off_bins + (size_t)3 * EH * 4;     // ~58.9 MB

    if (ws_size < need) {
        const size_t hbytes = (size_t)NNODES * NFEAT * sizeof(float);
        float* hw = (float*)d_ws;
        float* ho = (float*)d_out;
        dim3 blk(256), grd(((long)NEDGES * 16 + 255) / 256);
        hipMemcpyAsync(hw, h0, hbytes, hipMemcpyDeviceToDevice, stream);
        scatter_layer<<<grd, blk, 0, stream>>>(src, dst, wt, lw + 0L * NEDGES, h0, hw);
        hipMemcpyAsync(ho, h0, hbytes, hipMemcpyDeviceToDevice, stream);
        scatter_layer<<<grd, blk, 0, stream>>>(src, dst, wt, lw + 1L * NEDGES, hw, ho);
        hipMemcpyAsync(hw, h0, hbytes, hipMemcpyDeviceToDevice, stream);
        scatter_layer<<<grd, blk, 0, stream>>>(src, dst, wt, lw + 2L * NEDGES, ho, hw);
        hipMemsetAsync(ho, 0, hbytes, stream);
        scatter_layer<<<grd, blk, 0, stream>>>(src, dst, wt, lw + 3L * NEDGES, hw, ho);
        int n = NNODES * NFEAT;
        sigmoid_inplace<<<(n + 255) / 256, 256, 0, stream>>>(ho, n);
        return;
    }

    char* ws = (char*)d_ws;
    int*            cnt   = (int*)(ws + off_cnt);
    int*            tot   = (int*)(ws + off_tot);
    int*            bb    = (int*)(ws + off_bb);
    int*            offs1 = (int*)(ws + off_offs1);
    int*            offs2 = (int*)(ws + off_offs2);
    unsigned int*   csrA1 = (unsigned int*)(ws + off_csrA);
    unsigned int*   csrA2 = csrA1 + EH;
    unsigned short* wbase = (unsigned short*)(ws + off_w);
    unsigned short* w0_1 = wbase + 0L * EH; unsigned short* w1_1 = wbase + 1L * EH;
    unsigned short* w2_1 = wbase + 2L * EH; unsigned short* w3_1 = wbase + 3L * EH;
    unsigned short* w0_2 = wbase + 4L * EH; unsigned short* w1_2 = wbase + 5L * EH;
    unsigned short* w2_2 = wbase + 6L * EH; unsigned short* w3_2 = wbase + 7L * EH;
    unsigned int*   binsE = (unsigned int*)(ws + off_bins);
    // aliases over the dead bins region (alive only after both bucket_csr calls)
    const size_t HB = (size_t)NNODES * NFEAT * 2;   // 3.2 MB
    __half2* hb0  = (__half2*)(ws + off_bins);
    __half2* hbA  = (__half2*)(ws + off_bins + HB);
    __half2* hbB  = (__half2*)d_out;                // f16 scratch inside d_out
    float*   hout = (float*)d_out;

    // ---- build: two independent halves ----
    // half 1
    hist_chunk  <<<NCH, 256, 0, stream>>>(dst, 0, cnt);
    scan_chunks <<<NB,  512, 0, stream>>>(cnt, tot);
    scan_tot    <<<1,   256, 0, stream>>>(tot, bb);
    scatter_bins<<<NCH, 256, 0, stream>>>(src, dst, wt, lw, 0, cnt, bb, binsE);
    bucket_csr  <<<NB,  512, 0, stream>>>(bb, binsE, csrA1, w0_1, w1_1, w2_1, w3_1, offs1);
    // half 2
    hist_chunk  <<<NCH, 256, 0, stream>>>(dst, EH, cnt);
    scan_chunks <<<NB,  512, 0, stream>>>(cnt, tot);
    scan_tot    <<<1,   256, 0, stream>>>(tot, bb);
    scatter_bins<<<NCH, 256, 0, stream>>>(src, dst, wt, lw, EH, cnt, bb, binsE);
    bucket_csr  <<<NB,  512, 0, stream>>>(bb, binsE, csrA2, w0_2, w1_2, w2_2, w3_2, offs2);

    // ---- convert h0 to f16 (bins region now dead) ----
    conv16<<<(N8 + 255) / 256, 256, 0, stream>>>((const float2*)h0, hb0, N8);

    // ---- 4 layers: pull with in-wave combine ----
    dim3 blk(256), grdP((NNODES * 32) / 256);
    const float2* h0f2 = (const float2*)h0;
    pullr<false><<<grdP, blk, 0, stream>>>(offs1, offs2, csrA1, csrA2, w0_1, w0_2, hb0, h0f2, hbA);
    pullr<false><<<grdP, blk, 0, stream>>>(offs1, offs2, csrA1, csrA2, w1_1, w1_2, hbA, h0f2, hbB);
    pullr<false><<<grdP, blk, 0, stream>>>(offs1, offs2, csrA1, csrA2, w2_1, w2_2, hbB, h0f2, hbA);
    pullr<true ><<<grdP, blk, 0, stream>>>(offs1, offs2, csrA1, csrA2, w3_1, w3_2, hbA, h0f2, hout);
}

// Round 17
// 227.068 us; speedup vs baseline: 1.2262x; 1.0800x over previous
//
#include <hip/hip_runtime.h>
#include <hip/hip_fp16.h>

#define NNODES   100000
#define NFEAT    16
#define NEDGES   3200000
#define EH       1600000     // edges per half
#define NB       250         // dst buckets
#define NODES_PB 400         // 250*400 = 100000
#define NCHH     500         // chunks per half
#define NCH2     1000        // total chunks (both halves)
#define CHK      3200        // 1000*3200 = 3200000
#define CAP      7168        // per-bucket-half capacity (mean 6400, sigma~80 -> +9.6s)
#define N8       (NNODES * 8)   // half2 elements per h-plane

// ---------- K1: per-chunk bucket histogram (both halves, one launch) ----------
__global__ __launch_bounds__(256) void hist_chunk(
    const int* __restrict__ dst, int* __restrict__ cnt /*[NCH2][NB]*/)
{
    __shared__ int h[NB];
    int c = blockIdx.x;
    for (int i = threadIdx.x; i < NB; i += 256) h[i] = 0;
    __syncthreads();
    int base = c * CHK;
    for (int i = threadIdx.x; i < CHK; i += 256) {
        int d = dst[base + i];
        atomicAdd(&h[d / NODES_PB], 1);
    }
    __syncthreads();
    for (int i = threadIdx.x; i < NB; i += 256) cnt[c * NB + i] = h[i];
}

// ---------- K2: per-(half,bucket) exclusive scan over that half's chunks ----------
__global__ __launch_bounds__(512) void scan_chunks(
    int* __restrict__ cnt, int* __restrict__ tot /*[2][NB]*/)
{
    __shared__ int x[512];
    int half = blockIdx.x / NB;
    int b    = blockIdx.x % NB;
    int t = threadIdx.x;
    int v = (t < NCHH) ? cnt[(half * NCHH + t) * NB + b] : 0;
    x[t] = v;
    __syncthreads();
    for (int off = 1; off < 512; off <<= 1) {
        int y = (t >= off) ? x[t - off] : 0;
        __syncthreads();
        x[t] += y;
        __syncthreads();
    }
    if (t < NCHH) cnt[(half * NCHH + t) * NB + b] = x[t] - v;
    if (t == NCHH - 1) tot[half * NB + b] = x[t];
}

// ---------- K3: per-half exclusive scan of bucket totals -> bb[2][NB+1] ----------
__global__ __launch_bounds__(256) void scan_tot(
    const int* __restrict__ tot, int* __restrict__ bb)
{
    __shared__ int x[256];
    int half = blockIdx.x;
    const int* tt = tot + half * NB;
    int* bbh = bb + half * (NB + 1);
    int t = threadIdx.x;
    int v = (t < NB) ? tt[t] : 0;
    x[t] = v;
    __syncthreads();
    for (int off = 1; off < 256; off <<= 1) {
        int y = (t >= off) ? x[t - off] : 0;
        __syncthreads();
        x[t] += y;
        __syncthreads();
    }
    if (t < NB) bbh[t] = x[t] - v;
    if (t == NB - 1) bbh[NB] = x[t];
}

// ---------- K4: scatter edges into bucket-major AoS slots (both halves) ----------
// entry = 3 dwords: {src | dl<<17, half2(w0,w1), half2(w2,w3)}
__global__ __launch_bounds__(256) void scatter_bins(
    const int*   __restrict__ src,
    const int*   __restrict__ dst,
    const float* __restrict__ wt,
    const float* __restrict__ lw,
    const int*   __restrict__ cnt,
    const int*   __restrict__ bb,
    unsigned int* __restrict__ binsE /*[2][3*EH]*/)
{
    __shared__ int cur[NB];
    int c = blockIdx.x;
    int half = c / NCHH;
    const int* bbh = bb + half * (NB + 1);
    unsigned int* bE = binsE + (size_t)half * 3 * EH;
    for (int i = threadIdx.x; i < NB; i += 256)
        cur[i] = bbh[i] + cnt[c * NB + i];
    __syncthreads();
    int base = c * CHK;
    for (int i = threadIdx.x; i < CHK; i += 256) {
        int e = base + i;
        int d = dst[e];
        int b  = d / NODES_PB;
        int dl = d - b * NODES_PB;
        float w = wt[e];
        __half2 w01 = __floats2half2_rn(w * lw[e],              w * lw[NEDGES + e]);
        __half2 w23 = __floats2half2_rn(w * lw[2 * NEDGES + e], w * lw[3 * NEDGES + e]);
        int slot = atomicAdd(&cur[b], 1);
        unsigned int* p = bE + 3u * (unsigned int)slot;
        p[0] = (unsigned int)src[e] | ((unsigned int)dl << 17);
        p[1] = *(const unsigned int*)&w01;
        p[2] = *(const unsigned int*)&w23;
    }
}

// ---------- K5: per-bucket node sort (both halves), permutation in LDS ----------
__global__ __launch_bounds__(512) void bucket_csr(
    const int*          __restrict__ bb,
    const unsigned int* __restrict__ binsE,
    unsigned int*       __restrict__ csrA   /*[2][EH]*/,
    unsigned short*     __restrict__ wbase  /*[2][4][EH]*/,
    int*                __restrict__ offs   /*[2][NNODES+1]*/)
{
    __shared__ unsigned int   regA[CAP];
    __shared__ unsigned int   regC[CAP];
    __shared__ unsigned short pi[CAP];
    __shared__ int hist[NODES_PB];
    __shared__ int cur[NODES_PB];
    __shared__ int sc[512];                 // total ~75 KiB -> 2 blocks/CU
    int g = blockIdx.x, t = threadIdx.x;
    int half = g / NB;
    int b    = g % NB;
    const int* bbh = bb + half * (NB + 1);
    const unsigned int* bE = binsE + (size_t)half * 3 * EH;
    unsigned int*   cA = csrA + (size_t)half * EH;
    unsigned short* w0 = wbase + (size_t)(half * 4 + 0) * EH;
    unsigned short* w1 = wbase + (size_t)(half * 4 + 1) * EH;
    unsigned short* w2 = wbase + (size_t)(half * 4 + 2) * EH;
    unsigned short* w3 = wbase + (size_t)(half * 4 + 3) * EH;
    int* offsh = offs + half * (NNODES + 1);

    int e0 = bbh[b];
    int cnt = bbh[b + 1] - e0;
    if (cnt > CAP) cnt = CAP;               // statistically impossible; guards corruption

    for (int i = t; i < NODES_PB; i += 512) hist[i] = 0;
    __syncthreads();
    // P1: stage word0 + node histogram
    for (int i = t; i < cnt; i += 512) {
        unsigned int a = bE[3u * (unsigned int)(e0 + i)];
        regA[i] = a;
        atomicAdd(&hist[a >> 17], 1);
    }
    __syncthreads();
    // exclusive scan of 400 node counts
    int v = (t < NODES_PB) ? hist[t] : 0;
    sc[t] = v;
    __syncthreads();
    for (int off = 1; off < 512; off <<= 1) {
        int y = (t >= off) ? sc[t - off] : 0;
        __syncthreads();
        sc[t] += y;
        __syncthreads();
    }
    if (t < NODES_PB) {
        int excl = sc[t] - v;
        cur[t] = excl;
        offsh[b * NODES_PB + t] = e0 + excl;
    }
    if (b == 0 && t == 0) offsh[NNODES] = EH;
    __syncthreads();
    // P2: assign slots; pi (edge->slot) and inv (slot->edge) in LDS
    unsigned short* inv = (unsigned short*)regC;
    for (int i = t; i < cnt; i += 512) {
        unsigned int a = regA[i];
        int slot = atomicAdd(&cur[a >> 17], 1);
        pi[i]  = (unsigned short)slot;
        inv[slot] = (unsigned short)i;
    }
    __syncthreads();
    // P2b: flush csrA SEQUENTIALLY
    for (int s = t; s < cnt; s += 512) {
        cA[e0 + s] = regA[inv[s]] & 0x1FFFFu;
    }
    __syncthreads();
    // P3: read weight words once; scatter f16 halves into LDS planes at pi[i]
    unsigned short* wA0 = (unsigned short*)regA;
    unsigned short* wA1 = wA0 + CAP;
    unsigned short* wC2 = (unsigned short*)regC;
    unsigned short* wC3 = wC2 + CAP;
    for (int i = t; i < cnt; i += 512) {
        unsigned int u01 = bE[3u * (unsigned int)(e0 + i) + 1];
        unsigned int u23 = bE[3u * (unsigned int)(e0 + i) + 2];
        int s = pi[i];
        wA0[s] = (unsigned short)(u01 & 0xFFFFu);
        wA1[s] = (unsigned short)(u01 >> 16);
        wC2[s] = (unsigned short)(u23 & 0xFFFFu);
        wC3[s] = (unsigned short)(u23 >> 16);
    }
    __syncthreads();
    // P4: flush all four planes SEQUENTIALLY
    for (int s = t; s < cnt; s += 512) {
        w0[e0 + s] = wA0[s];
        w1[e0 + s] = wA1[s];
        w2[e0 + s] = wC2[s];
        w3[e0 + s] = wC3[s];
    }
}

// ---------- K5b: convert h0 (f32) -> f16 table ----------
__global__ __launch_bounds__(256) void conv16(
    const float2* __restrict__ in, __half2* __restrict__ out, int n2)
{
    int i = blockIdx.x * 256 + threadIdx.x;
    if (i < n2) {
        float2 v = in[i];
        out[i] = __floats2half2_rn(v.x, v.y);
    }
}

// ---------- K6: pull with in-wave combine ----------
// thread map: n = t>>5, grp = (t>>3)&3, f2 = t&7.  One 64-lane wave = 2 nodes;
// the 4 quarter-groups of a node are lane bits 3-4 -> __shfl_xor(8/16) reduce.
template<bool SIG>
__global__ __launch_bounds__(256) void pullr(
    const int*            __restrict__ offs1,
    const int*            __restrict__ offs2,
    const unsigned int*   __restrict__ csrA1,
    const unsigned int*   __restrict__ csrA2,
    const unsigned short* __restrict__ wk1,
    const unsigned short* __restrict__ wk2,
    const __half2*        __restrict__ h16,   // [N8]
    const float2*         __restrict__ h0,    // residual (unused if SIG)
    void*                 __restrict__ hout)
{
    int t = blockIdx.x * 256 + threadIdx.x;
    int n = t >> 5;
    if (n >= NNODES) return;
    int grp = (t >> 3) & 3;
    int f2  = t & 7;

    int j01 = offs1[n], e1 = offs1[n + 1];
    int j02 = offs2[n], e2 = offs2[n + 1];
    int m1 = (j01 + e1) >> 1;
    int m2 = (j02 + e2) >> 1;

    const unsigned int*   A;
    const unsigned short* W;
    int js, je;
    if (grp < 2) {
        A = csrA1; W = wk1;
        js = (grp == 0) ? j01 : m1;
        je = (grp == 0) ? m1  : e1;
    } else {
        A = csrA2; W = wk2;
        js = (grp == 2) ? j02 : m2;
        je = (grp == 2) ? m2  : e2;
    }

    float ax = 0.f, ay = 0.f;
    int j = js;
    for (; j + 3 < je; j += 4) {
        unsigned int s0 = A[j],     s1 = A[j + 1];
        unsigned int s2 = A[j + 2], s3 = A[j + 3];
        float w0 = __half2float(__ushort_as_half(W[j]));
        float w1 = __half2float(__ushort_as_half(W[j + 1]));
        float w2 = __half2float(__ushort_as_half(W[j + 2]));
        float w3 = __half2float(__ushort_as_half(W[j + 3]));
        float2 v0 = __half22float2(h16[s0 * 8 + f2]);
        float2 v1 = __half22float2(h16[s1 * 8 + f2]);
        float2 v2 = __half22float2(h16[s2 * 8 + f2]);
        float2 v3 = __half22float2(h16[s3 * 8 + f2]);
        ax = fmaf(w0, v0.x, ax); ay = fmaf(w0, v0.y, ay);
        ax = fmaf(w1, v1.x, ax); ay = fmaf(w1, v1.y, ay);
        ax = fmaf(w2, v2.x, ax); ay = fmaf(w2, v2.y, ay);
        ax = fmaf(w3, v3.x, ax); ay = fmaf(w3, v3.y, ay);
    }
    for (; j < je; ++j) {
        unsigned int s = A[j];
        float w = __half2float(__ushort_as_half(W[j]));
        float2 v = __half22float2(h16[s * 8 + f2]);
        ax = fmaf(w, v.x, ax); ay = fmaf(w, v.y, ay);
    }

    // reduce the 4 groups in-wave (f32)
    ax += __shfl_xor(ax, 8);  ay += __shfl_xor(ay, 8);
    ax += __shfl_xor(ax, 16); ay += __shfl_xor(ay, 16);

    if (grp == 0) {
        int o = n * 8 + f2;
        if (SIG) {
            float2 r;
            r.x = 1.f / (1.f + expf(-2.f * ax));
            r.y = 1.f / (1.f + expf(-2.f * ay));
            ((float2*)hout)[o] = r;
        } else {
            float2 b = h0[o];
            ((__half2*)hout)[o] = __floats2half2_rn(ax + b.x, ay + b.y);
        }
    }
}

// ---------------- fallback (atomic push path, needs only 6.4 MB ws) ----------------
__global__ __launch_bounds__(256) void scatter_layer(
    const int* __restrict__ src, const int* __restrict__ dst,
    const float* __restrict__ wt, const float* __restrict__ lw,
    const float* __restrict__ h, float* __restrict__ acc)
{
    long t = (long)blockIdx.x * blockDim.x + threadIdx.x;
    int e = (int)(t >> 4);
    if (e >= NEDGES) return;
    int f = (int)(t & 15);
    float w = wt[e] * lw[e];
    atomicAdd(&acc[dst[e] * NFEAT + f], w * h[src[e] * NFEAT + f]);
}
__global__ __launch_bounds__(256) void sigmoid_inplace(float* __restrict__ out, int n)
{
    int i = blockIdx.x * blockDim.x + threadIdx.x;
    if (i < n) out[i] = 1.f / (1.f + expf(-2.f * out[i]));
}

// ---------------- launch ----------------
extern "C" void kernel_launch(void* const* d_in, const int* in_sizes, int n_in,
                              void* d_out, int out_size, void* d_ws, size_t ws_size,
                              hipStream_t stream)
{
    const float* h0 = (const float*)d_in[0];
    const int*   ei = (const int*)d_in[1];     // int32 (JAX x64 off)
    const float* wt = (const float*)d_in[2];
    const float* lw = (const float*)d_in[3];

    const int* src = ei;
    const int* dst = ei + NEDGES;

    // workspace layout (bytes)
    const size_t off_cnt  = 0;                                  // int[1000*250] = 1,000,000
    const size_t off_tot  = 1000064;                            // int[2*250]
    const size_t off_bb   = 1002112;                            // int[2*251]
    const size_t off_offs = 1004160;                            // int[2*100001] = 800,008
    const size_t off_csrA = 1804288;                            // u32[2*EH]    12.8 MB
    const size_t off_w    = off_csrA + (size_t)2 * EH * 4;      // f16[2][4][EH] 25.6 MB
    const size_t off_bins = off_w + (size_t)8 * EH * 2;         // u32[2][3*EH]  38.4 MB
    const size_t need     = off_bins + (size_t)2 * 3 * EH * 4;  // ~78.6 MB

    if (ws_size < need) {
        const size_t hbytes = (size_t)NNODES * NFEAT * sizeof(float);
        float* hw = (float*)d_ws;
        float* ho = (float*)d_out;
        dim3 blk(256), grd(((long)NEDGES * 16 + 255) / 256);
        hipMemcpyAsync(hw, h0, hbytes, hipMemcpyDeviceToDevice, stream);
        scatter_layer<<<grd, blk, 0, stream>>>(src, dst, wt, lw + 0L * NEDGES, h0, hw);
        hipMemcpyAsync(ho, h0, hbytes, hipMemcpyDeviceToDevice, stream);
        scatter_layer<<<grd, blk, 0, stream>>>(src, dst, wt, lw + 1L * NEDGES, hw, ho);
        hipMemcpyAsync(hw, h0, hbytes, hipMemcpyDeviceToDevice, stream);
        scatter_layer<<<grd, blk, 0, stream>>>(src, dst, wt, lw + 2L * NEDGES, ho, hw);
        hipMemsetAsync(ho, 0, hbytes, stream);
        scatter_layer<<<grd, blk, 0, stream>>>(src, dst, wt, lw + 3L * NEDGES, hw, ho);
        int n = NNODES * NFEAT;
        sigmoid_inplace<<<(n + 255) / 256, 256, 0, stream>>>(ho, n);
        return;
    }

    char* ws = (char*)d_ws;
    int*            cnt   = (int*)(ws + off_cnt);
    int*            tot   = (int*)(ws + off_tot);
    int*            bb    = (int*)(ws + off_bb);
    int*            offs  = (int*)(ws + off_offs);
    int*            offs1 = offs;
    int*            offs2 = offs + (NNODES + 1);
    unsigned int*   csrA  = (unsigned int*)(ws + off_csrA);
    unsigned int*   csrA1 = csrA;
    unsigned int*   csrA2 = csrA + EH;
    unsigned short* wbase = (unsigned short*)(ws + off_w);
    unsigned short* w0_1 = wbase + 0L * EH; unsigned short* w1_1 = wbase + 1L * EH;
    unsigned short* w2_1 = wbase + 2L * EH; unsigned short* w3_1 = wbase + 3L * EH;
    unsigned short* w0_2 = wbase + 4L * EH; unsigned short* w1_2 = wbase + 5L * EH;
    unsigned short* w2_2 = wbase + 6L * EH; unsigned short* w3_2 = wbase + 7L * EH;
    unsigned int*   binsE = (unsigned int*)(ws + off_bins);
    // aliases over the dead bins region (alive only after bucket_csr)
    const size_t HB = (size_t)NNODES * NFEAT * 2;   // 3.2 MB
    __half2* hb0  = (__half2*)(ws + off_bins);
    __half2* hbA  = (__half2*)(ws + off_bins + HB);
    __half2* hbB  = (__half2*)d_out;                // f16 scratch inside d_out
    float*   hout = (float*)d_out;

    // ---- build: both halves fused into single launches ----
    hist_chunk  <<<NCH2,   256, 0, stream>>>(dst, cnt);
    scan_chunks <<<2 * NB, 512, 0, stream>>>(cnt, tot);
    scan_tot    <<<2,      256, 0, stream>>>(tot, bb);
    scatter_bins<<<NCH2,   256, 0, stream>>>(src, dst, wt, lw, cnt, bb, binsE);
    bucket_csr  <<<2 * NB, 512, 0, stream>>>(bb, binsE, csrA, wbase, offs);

    // ---- convert h0 to f16 (bins region now dead) ----
    conv16<<<(N8 + 255) / 256, 256, 0, stream>>>((const float2*)h0, hb0, N8);

    // ---- 4 layers: pull with in-wave combine ----
    dim3 blk(256), grdP((NNODES * 32) / 256);
    const float2* h0f2 = (const float2*)h0;
    pullr<false><<<grdP, blk, 0, stream>>>(offs1, offs2, csrA1, csrA2, w0_1, w0_2, hb0, h0f2, hbA);
    pullr<false><<<grdP, blk, 0, stream>>>(offs1, offs2, csrA1, csrA2, w1_1, w1_2, hbA, h0f2, hbB);
    pullr<false><<<grdP, blk, 0, stream>>>(offs1, offs2, csrA1, csrA2, w2_1, w2_2, hbB, h0f2, hbA);
    pullr<true ><<<grdP, blk, 0, stream>>>(offs1, offs2, csrA1, csrA2, w3_1, w3_2, hbA, h0f2, hout);
}

// Round 18
// 207.815 us; speedup vs baseline: 1.3398x; 1.0926x over previous
//
#include <hip/hip_runtime.h>
#include <hip/hip_fp16.h>

#define NNODES   100000
#define NFEAT    16
#define NEDGES   3200000
#define EH       1600000     // edges per half
#define NB       250         // dst buckets
#define NODES_PB 400         // 250*400 = 100000
#define NCHH     500         // chunks per half
#define NCH2     1000        // total chunks (both halves)
#define CHK      3200        // 1000*3200 = 3200000
#define CAP      7168        // per-bucket-half capacity (mean 6400, sigma~80 -> +9.6s)
#define N8       (NNODES * 8)   // half2 elements per h-plane

// ---------- K1: per-chunk bucket histogram (both halves, one launch) ----------
__global__ __launch_bounds__(256) void hist_chunk(
    const int* __restrict__ dst, int* __restrict__ cnt /*[NCH2][NB]*/)
{
    __shared__ int h[NB];
    int c = blockIdx.x;
    for (int i = threadIdx.x; i < NB; i += 256) h[i] = 0;
    __syncthreads();
    int base = c * CHK;
    for (int i = threadIdx.x; i < CHK; i += 256) {
        int d = dst[base + i];
        atomicAdd(&h[d / NODES_PB], 1);
    }
    __syncthreads();
    for (int i = threadIdx.x; i < NB; i += 256) cnt[c * NB + i] = h[i];
}

// ---------- K2: per-(half,bucket) exclusive scan over that half's chunks ----------
__global__ __launch_bounds__(512) void scan_chunks(
    int* __restrict__ cnt, int* __restrict__ tot /*[2][NB]*/)
{
    __shared__ int x[512];
    int half = blockIdx.x / NB;
    int b    = blockIdx.x % NB;
    int t = threadIdx.x;
    int v = (t < NCHH) ? cnt[(half * NCHH + t) * NB + b] : 0;
    x[t] = v;
    __syncthreads();
    for (int off = 1; off < 512; off <<= 1) {
        int y = (t >= off) ? x[t - off] : 0;
        __syncthreads();
        x[t] += y;
        __syncthreads();
    }
    if (t < NCHH) cnt[(half * NCHH + t) * NB + b] = x[t] - v;
    if (t == NCHH - 1) tot[half * NB + b] = x[t];
}

// ---------- K3: per-half exclusive scan of bucket totals -> bb[2][NB+1] ----------
__global__ __launch_bounds__(256) void scan_tot(
    const int* __restrict__ tot, int* __restrict__ bb)
{
    __shared__ int x[256];
    int half = blockIdx.x;
    const int* tt = tot + half * NB;
    int* bbh = bb + half * (NB + 1);
    int t = threadIdx.x;
    int v = (t < NB) ? tt[t] : 0;
    x[t] = v;
    __syncthreads();
    for (int off = 1; off < 256; off <<= 1) {
        int y = (t >= off) ? x[t - off] : 0;
        __syncthreads();
        x[t] += y;
        __syncthreads();
    }
    if (t < NB) bbh[t] = x[t] - v;
    if (t == NB - 1) bbh[NB] = x[t];
}

// ---------- K4: LDS-staged scatter with run-coalesced flush ----------
// entry = 3 dwords: {src | dl<<17, half2(w0,w1), half2(w2,w3)}
__global__ __launch_bounds__(512) void scatter_bins(
    const int*   __restrict__ src,
    const int*   __restrict__ dst,
    const float* __restrict__ wt,
    const float* __restrict__ lw,
    const int*   __restrict__ cnt,
    const int*   __restrict__ tot,
    const int*   __restrict__ bb,
    unsigned int* __restrict__ binsE /*[2][3*EH]*/)
{
    __shared__ unsigned int   sE[CHK * 3];   // 38400 B, bucket-major entries
    __shared__ unsigned short sB[CHK];       // 6400 B, entry -> bucket
    __shared__ int lhist[NB];                // this chunk's per-bucket count
    __shared__ int loff[NB];                 // within-chunk bucket-major offsets
    __shared__ int lcur[NB];
    __shared__ int gmb[NB];                  // global base - loff  (flush addend)
    __shared__ int x[512];

    int c = blockIdx.x;
    int t = threadIdx.x;
    int half = c / NCHH;
    int cc   = c % NCHH;
    const int* bbh = bb + half * (NB + 1);
    unsigned int* bE = binsE + (size_t)half * 3 * EH;

    // derive this chunk's per-bucket run lengths from the scanned cnt table
    for (int i = t; i < NB; i += 512) {
        int cur0 = cnt[c * NB + i];
        int nxt  = (cc == NCHH - 1) ? tot[half * NB + i] : cnt[(c + 1) * NB + i];
        lhist[i] = nxt - cur0;
        gmb[i]   = bbh[i] + cur0;            // global run base (loff subtracted below)
    }
    __syncthreads();
    // exclusive scan of lhist -> loff
    int v = (t < NB) ? lhist[t] : 0;
    x[t] = v;
    __syncthreads();
    for (int off = 1; off < 512; off <<= 1) {
        int y = (t >= off) ? x[t - off] : 0;
        __syncthreads();
        x[t] += y;
        __syncthreads();
    }
    if (t < NB) {
        int excl = x[t] - v;
        loff[t] = excl;
        lcur[t] = excl;
        gmb[t] -= excl;                      // g = gmb[b] + s
    }
    __syncthreads();

    // pass: read edges, stage bucket-major into LDS
    int base = c * CHK;
    for (int i = t; i < CHK; i += 512) {
        int e = base + i;
        int d = dst[e];
        int b  = d / NODES_PB;
        int dl = d - b * NODES_PB;
        float w = wt[e];
        __half2 w01 = __floats2half2_rn(w * lw[e],              w * lw[NEDGES + e]);
        __half2 w23 = __floats2half2_rn(w * lw[2 * NEDGES + e], w * lw[3 * NEDGES + e]);
        int slot = atomicAdd(&lcur[b], 1);
        sE[3 * slot + 0] = (unsigned int)src[e] | ((unsigned int)dl << 17);
        sE[3 * slot + 1] = *(const unsigned int*)&w01;
        sE[3 * slot + 2] = *(const unsigned int*)&w23;
        sB[slot] = (unsigned short)b;
    }
    __syncthreads();

    // flush: consecutive threads -> consecutive global slots within runs
    for (int s = t; s < CHK; s += 512) {
        int b = sB[s];
        unsigned int g = (unsigned int)(gmb[b] + s);
        unsigned int* p = bE + 3u * g;
        p[0] = sE[3 * s + 0];
        p[1] = sE[3 * s + 1];
        p[2] = sE[3 * s + 2];
    }
}

// ---------- K5: per-bucket node sort (both halves), permutation in LDS ----------
__global__ __launch_bounds__(512) void bucket_csr(
    const int*          __restrict__ bb,
    const unsigned int* __restrict__ binsE,
    unsigned int*       __restrict__ csrA   /*[2][EH]*/,
    unsigned short*     __restrict__ wbase  /*[2][4][EH]*/,
    int*                __restrict__ offs   /*[2][NNODES+1]*/)
{
    __shared__ unsigned int   regA[CAP];
    __shared__ unsigned int   regC[CAP];
    __shared__ unsigned short pi[CAP];
    __shared__ int hist[NODES_PB];
    __shared__ int cur[NODES_PB];
    __shared__ int sc[512];                 // total ~75 KiB -> 2 blocks/CU
    int g = blockIdx.x, t = threadIdx.x;
    int half = g / NB;
    int b    = g % NB;
    const int* bbh = bb + half * (NB + 1);
    const unsigned int* bE = binsE + (size_t)half * 3 * EH;
    unsigned int*   cA = csrA + (size_t)half * EH;
    unsigned short* w0 = wbase + (size_t)(half * 4 + 0) * EH;
    unsigned short* w1 = wbase + (size_t)(half * 4 + 1) * EH;
    unsigned short* w2 = wbase + (size_t)(half * 4 + 2) * EH;
    unsigned short* w3 = wbase + (size_t)(half * 4 + 3) * EH;
    int* offsh = offs + half * (NNODES + 1);

    int e0 = bbh[b];
    int cnt = bbh[b + 1] - e0;
    if (cnt > CAP) cnt = CAP;               // statistically impossible; guards corruption

    for (int i = t; i < NODES_PB; i += 512) hist[i] = 0;
    __syncthreads();
    // P1: stage word0 + node histogram
    for (int i = t; i < cnt; i += 512) {
        unsigned int a = bE[3u * (unsigned int)(e0 + i)];
        regA[i] = a;
        atomicAdd(&hist[a >> 17], 1);
    }
    __syncthreads();
    // exclusive scan of 400 node counts
    int v = (t < NODES_PB) ? hist[t] : 0;
    sc[t] = v;
    __syncthreads();
    for (int off = 1; off < 512; off <<= 1) {
        int y = (t >= off) ? sc[t - off] : 0;
        __syncthreads();
        sc[t] += y;
        __syncthreads();
    }
    if (t < NODES_PB) {
        int excl = sc[t] - v;
        cur[t] = excl;
        offsh[b * NODES_PB + t] = e0 + excl;
    }
    if (b == 0 && t == 0) offsh[NNODES] = EH;
    __syncthreads();
    // P2: assign slots; pi (edge->slot) and inv (slot->edge) in LDS
    unsigned short* inv = (unsigned short*)regC;
    for (int i = t; i < cnt; i += 512) {
        unsigned int a = regA[i];
        int slot = atomicAdd(&cur[a >> 17], 1);
        pi[i]  = (unsigned short)slot;
        inv[slot] = (unsigned short)i;
    }
    __syncthreads();
    // P2b: flush csrA SEQUENTIALLY
    for (int s = t; s < cnt; s += 512) {
        cA[e0 + s] = regA[inv[s]] & 0x1FFFFu;
    }
    __syncthreads();
    // P3: read weight words once; scatter f16 halves into LDS planes at pi[i]
    unsigned short* wA0 = (unsigned short*)regA;
    unsigned short* wA1 = wA0 + CAP;
    unsigned short* wC2 = (unsigned short*)regC;
    unsigned short* wC3 = wC2 + CAP;
    for (int i = t; i < cnt; i += 512) {
        unsigned int u01 = bE[3u * (unsigned int)(e0 + i) + 1];
        unsigned int u23 = bE[3u * (unsigned int)(e0 + i) + 2];
        int s = pi[i];
        wA0[s] = (unsigned short)(u01 & 0xFFFFu);
        wA1[s] = (unsigned short)(u01 >> 16);
        wC2[s] = (unsigned short)(u23 & 0xFFFFu);
        wC3[s] = (unsigned short)(u23 >> 16);
    }
    __syncthreads();
    // P4: flush all four planes SEQUENTIALLY
    for (int s = t; s < cnt; s += 512) {
        w0[e0 + s] = wA0[s];
        w1[e0 + s] = wA1[s];
        w2[e0 + s] = wC2[s];
        w3[e0 + s] = wC3[s];
    }
}

// ---------- K5b: convert h0 (f32) -> f16 table ----------
__global__ __launch_bounds__(256) void conv16(
    const float2* __restrict__ in, __half2* __restrict__ out, int n2)
{
    int i = blockIdx.x * 256 + threadIdx.x;
    if (i < n2) {
        float2 v = in[i];
        out[i] = __floats2half2_rn(v.x, v.y);
    }
}

// ---------- K6: pull with in-wave combine ----------
// thread map: n = t>>5, grp = (t>>3)&3, f2 = t&7.  One 64-lane wave = 2 nodes;
// the 4 quarter-groups of a node are lane bits 3-4 -> __shfl_xor(8/16) reduce.
template<bool SIG>
__global__ __launch_bounds__(256) void pullr(
    const int*            __restrict__ offs1,
    const int*            __restrict__ offs2,
    const unsigned int*   __restrict__ csrA1,
    const unsigned int*   __restrict__ csrA2,
    const unsigned short* __restrict__ wk1,
    const unsigned short* __restrict__ wk2,
    const __half2*        __restrict__ h16,   // [N8]
    const float2*         __restrict__ h0,    // residual (unused if SIG)
    void*                 __restrict__ hout)
{
    int t = blockIdx.x * 256 + threadIdx.x;
    int n = t >> 5;
    if (n >= NNODES) return;
    int grp = (t >> 3) & 3;
    int f2  = t & 7;

    int j01 = offs1[n], e1 = offs1[n + 1];
    int j02 = offs2[n], e2 = offs2[n + 1];
    int m1 = (j01 + e1) >> 1;
    int m2 = (j02 + e2) >> 1;

    const unsigned int*   A;
    const unsigned short* W;
    int js, je;
    if (grp < 2) {
        A = csrA1; W = wk1;
        js = (grp == 0) ? j01 : m1;
        je = (grp == 0) ? m1  : e1;
    } else {
        A = csrA2; W = wk2;
        js = (grp == 2) ? j02 : m2;
        je = (grp == 2) ? m2  : e2;
    }

    float ax = 0.f, ay = 0.f;
    int j = js;
    for (; j + 3 < je; j += 4) {
        unsigned int s0 = A[j],     s1 = A[j + 1];
        unsigned int s2 = A[j + 2], s3 = A[j + 3];
        float w0 = __half2float(__ushort_as_half(W[j]));
        float w1 = __half2float(__ushort_as_half(W[j + 1]));
        float w2 = __half2float(__ushort_as_half(W[j + 2]));
        float w3 = __half2float(__ushort_as_half(W[j + 3]));
        float2 v0 = __half22float2(h16[s0 * 8 + f2]);
        float2 v1 = __half22float2(h16[s1 * 8 + f2]);
        float2 v2 = __half22float2(h16[s2 * 8 + f2]);
        float2 v3 = __half22float2(h16[s3 * 8 + f2]);
        ax = fmaf(w0, v0.x, ax); ay = fmaf(w0, v0.y, ay);
        ax = fmaf(w1, v1.x, ax); ay = fmaf(w1, v1.y, ay);
        ax = fmaf(w2, v2.x, ax); ay = fmaf(w2, v2.y, ay);
        ax = fmaf(w3, v3.x, ax); ay = fmaf(w3, v3.y, ay);
    }
    for (; j < je; ++j) {
        unsigned int s = A[j];
        float w = __half2float(__ushort_as_half(W[j]));
        float2 v = __half22float2(h16[s * 8 + f2]);
        ax = fmaf(w, v.x, ax); ay = fmaf(w, v.y, ay);
    }

    // reduce the 4 groups in-wave (f32)
    ax += __shfl_xor(ax, 8);  ay += __shfl_xor(ay, 8);
    ax += __shfl_xor(ax, 16); ay += __shfl_xor(ay, 16);

    if (grp == 0) {
        int o = n * 8 + f2;
        if (SIG) {
            float2 r;
            r.x = 1.f / (1.f + expf(-2.f * ax));
            r.y = 1.f / (1.f + expf(-2.f * ay));
            ((float2*)hout)[o] = r;
        } else {
            float2 b = h0[o];
            ((__half2*)hout)[o] = __floats2half2_rn(ax + b.x, ay + b.y);
        }
    }
}

// ---------------- fallback (atomic push path, needs only 6.4 MB ws) ----------------
__global__ __launch_bounds__(256) void scatter_layer(
    const int* __restrict__ src, const int* __restrict__ dst,
    const float* __restrict__ wt, const float* __restrict__ lw,
    const float* __restrict__ h, float* __restrict__ acc)
{
    long t = (long)blockIdx.x * blockDim.x + threadIdx.x;
    int e = (int)(t >> 4);
    if (e >= NEDGES) return;
    int f = (int)(t & 15);
    float w = wt[e] * lw[e];
    atomicAdd(&acc[dst[e] * NFEAT + f], w * h[src[e] * NFEAT + f]);
}
__global__ __launch_bounds__(256) void sigmoid_inplace(float* __restrict__ out, int n)
{
    int i = blockIdx.x * blockDim.x + threadIdx.x;
    if (i < n) out[i] = 1.f / (1.f + expf(-2.f * out[i]));
}

// ---------------- launch ----------------
extern "C" void kernel_launch(void* const* d_in, const int* in_sizes, int n_in,
                              void* d_out, int out_size, void* d_ws, size_t ws_size,
                              hipStream_t stream)
{
    const float* h0 = (const float*)d_in[0];
    const int*   ei = (const int*)d_in[1];     // int32 (JAX x64 off)
    const float* wt = (const float*)d_in[2];
    const float* lw = (const float*)d_in[3];

    const int* src = ei;
    const int* dst = ei + NEDGES;

    // workspace layout (bytes)
    const size_t off_cnt  = 0;                                  // int[1000*250] = 1,000,000
    const size_t off_tot  = 1000064;                            // int[2*250]
    const size_t off_bb   = 1002112;                            // int[2*251]
    const size_t off_offs = 1004160;                            // int[2*100001] = 800,008
    const size_t off_csrA = 1804288;                            // u32[2*EH]    12.8 MB
    const size_t off_w    = off_csrA + (size_t)2 * EH * 4;      // f16[2][4][EH] 25.6 MB
    const size_t off_bins = off_w + (size_t)8 * EH * 2;         // u32[2][3*EH]  38.4 MB
    const size_t need     = off_bins + (size_t)2 * 3 * EH * 4;  // ~78.6 MB

    if (ws_size < need) {
        const size_t hbytes = (size_t)NNODES * NFEAT * sizeof(float);
        float* hw = (float*)d_ws;
        float* ho = (float*)d_out;
        dim3 blk(256), grd(((long)NEDGES * 16 + 255) / 256);
        hipMemcpyAsync(hw, h0, hbytes, hipMemcpyDeviceToDevice, stream);
        scatter_layer<<<grd, blk, 0, stream>>>(src, dst, wt, lw + 0L * NEDGES, h0, hw);
        hipMemcpyAsync(ho, h0, hbytes, hipMemcpyDeviceToDevice, stream);
        scatter_layer<<<grd, blk, 0, stream>>>(src, dst, wt, lw + 1L * NEDGES, hw, ho);
        hipMemcpyAsync(hw, h0, hbytes, hipMemcpyDeviceToDevice, stream);
        scatter_layer<<<grd, blk, 0, stream>>>(src, dst, wt, lw + 2L * NEDGES, ho, hw);
        hipMemsetAsync(ho, 0, hbytes, stream);
        scatter_layer<<<grd, blk, 0, stream>>>(src, dst, wt, lw + 3L * NEDGES, hw, ho);
        int n = NNODES * NFEAT;
        sigmoid_inplace<<<(n + 255) / 256, 256, 0, stream>>>(ho, n);
        return;
    }

    char* ws = (char*)d_ws;
    int*            cnt   = (int*)(ws + off_cnt);
    int*            tot   = (int*)(ws + off_tot);
    int*            bb    = (int*)(ws + off_bb);
    int*            offs  = (int*)(ws + off_offs);
    int*            offs1 = offs;
    int*            offs2 = offs + (NNODES + 1);
    unsigned int*   csrA  = (unsigned int*)(ws + off_csrA);
    unsigned int*   csrA1 = csrA;
    unsigned int*   csrA2 = csrA + EH;
    unsigned short* wbase = (unsigned short*)(ws + off_w);
    unsigned short* w0_1 = wbase + 0L * EH; unsigned short* w1_1 = wbase + 1L * EH;
    unsigned short* w2_1 = wbase + 2L * EH; unsigned short* w3_1 = wbase + 3L * EH;
    unsigned short* w0_2 = wbase + 4L * EH; unsigned short* w1_2 = wbase + 5L * EH;
    unsigned short* w2_2 = wbase + 6L * EH; unsigned short* w3_2 = wbase + 7L * EH;
    unsigned int*   binsE = (unsigned int*)(ws + off_bins);
    // aliases over the dead bins region (alive only after bucket_csr)
    const size_t HB = (size_t)NNODES * NFEAT * 2;   // 3.2 MB
    __half2* hb0  = (__half2*)(ws + off_bins);
    __half2* hbA  = (__half2*)(ws + off_bins + HB);
    __half2* hbB  = (__half2*)d_out;                // f16 scratch inside d_out
    float*   hout = (float*)d_out;

    // ---- build: both halves fused into single launches ----
    hist_chunk  <<<NCH2,   256, 0, stream>>>(dst, cnt);
    scan_chunks <<<2 * NB, 512, 0, stream>>>(cnt, tot);
    scan_tot    <<<2,      256, 0, stream>>>(tot, bb);
    scatter_bins<<<NCH2,   512, 0, stream>>>(src, dst, wt, lw, cnt, tot, bb, binsE);
    bucket_csr  <<<2 * NB, 512, 0, stream>>>(bb, binsE, csrA, wbase, offs);

    // ---- convert h0 to f16 (bins region now dead) ----
    conv16<<<(N8 + 255) / 256, 256, 0, stream>>>((const float2*)h0, hb0, N8);

    // ---- 4 layers: pull with in-wave combine ----
    dim3 blk(256), grdP((NNODES * 32) / 256);
    const float2* h0f2 = (const float2*)h0;
    pullr<false><<<grdP, blk, 0, stream>>>(offs1, offs2, csrA1, csrA2, w0_1, w0_2, hb0, h0f2, hbA);
    pullr<false><<<grdP, blk, 0, stream>>>(offs1, offs2, csrA1, csrA2, w1_1, w1_2, hbA, h0f2, hbB);
    pullr<false><<<grdP, blk, 0, stream>>>(offs1, offs2, csrA1, csrA2, w2_1, w2_2, hbB, h0f2, hbA);
    pullr<true ><<<grdP, blk, 0, stream>>>(offs1, offs2, csrA1, csrA2, w3_1, w3_2, hbA, h0f2, hout);
}